// Round 12
// baseline (648.571 us; speedup 1.0000x reference)
//
// build-salt: r12-cgemm-v3
#include <hip/hip_runtime.h>
#include <math.h>

#define N_PER 25000
#define HID 256
#define E_PER 200000

typedef unsigned short ushort_t;
typedef __attribute__((ext_vector_type(8))) unsigned short ushort8v;
typedef __attribute__((ext_vector_type(4))) unsigned short ushort4v;
typedef __attribute__((ext_vector_type(8))) __bf16 bf16x8;
typedef __attribute__((ext_vector_type(4))) float floatx4;

__device__ __forceinline__ float bf2f(unsigned short u) {
    union { unsigned int i; float f; } c; c.i = ((unsigned int)u) << 16; return c.f;
}
__device__ __forceinline__ unsigned short f2bf(float f) {
    union { float f; unsigned int i; } c; c.f = f;
    unsigned int i = c.i;
    return (unsigned short)((i + 0x7FFFu + ((i >> 16) & 1u)) >> 16);
}

// fast GELU: x * sigmoid(1.5957691 * (x + 0.044715 x^3))  (tanh-form approx)
__device__ __forceinline__ float fast_gelu(float x) {
    float u = 1.595769122f * x * (1.f + 0.044715f * x * x);
    float e = __expf(-u);
    return x * __builtin_amdgcn_rcpf(1.f + e);
}

// ---------------- degree counting ----------------
__global__ void k_count(const int* __restrict__ es, const int* __restrict__ ed,
                        int* __restrict__ cnt_s, int* __restrict__ cnt_d) {
    int i = blockIdx.x * 256 + threadIdx.x;
    if (i >= 2 * E_PER) return;
    int et = i / E_PER;
    atomicAdd(&cnt_s[et * N_PER + es[i]], 1);
    atomicAdd(&cnt_d[et * N_PER + ed[i]], 1);
}

__global__ void k_scale(const int* __restrict__ cnt_s, const int* __restrict__ cnt_d,
                        float* __restrict__ cs, float* __restrict__ cd) {
    int i = blockIdx.x * 256 + threadIdx.x;
    if (i >= 2 * N_PER) return;
    cs[i] = rsqrtf(fmaxf((float)cnt_s[i], 1.f));
    cd[i] = rsqrtf(fmaxf((float)cnt_d[i], 1.f));
}

// ---------------- CSR build: scan + fill ----------------
__global__ __launch_bounds__(1024) void k_scan(const int* __restrict__ cnt,
                                               int* __restrict__ off, int* __restrict__ cur) {
    int et = blockIdx.x, t = threadIdx.x;
    const int* c = cnt + et * N_PER;
    int loc[25]; int tot = 0;
#pragma unroll
    for (int j = 0; j < 25; j++) {
        int idx = t * 25 + j;
        int v = (idx < N_PER) ? c[idx] : 0;
        loc[j] = tot; tot += v;
    }
    __shared__ int sb[1024];
    sb[t] = tot; __syncthreads();
    for (int d = 1; d < 1024; d <<= 1) {
        int v = (t >= d) ? sb[t - d] : 0;
        __syncthreads();
        sb[t] += v;
        __syncthreads();
    }
    int base = sb[t] - tot;
#pragma unroll
    for (int j = 0; j < 25; j++) {
        int idx = t * 25 + j;
        if (idx <= N_PER) {
            int val = base + loc[j];
            off[et * (N_PER + 1) + idx] = val;
            if (idx < N_PER) cur[et * N_PER + idx] = val;
        }
    }
}

__global__ void k_fill(const int* __restrict__ es, const int* __restrict__ ed,
                       int* __restrict__ cur, int* __restrict__ csr) {
    int i = blockIdx.x * 256 + threadIdx.x;
    if (i >= 2 * E_PER) return;
    int et = i / E_PER;
    int d = ed[i];
    int pos = atomicAdd(&cur[et * N_PER + d], 1);
    csr[et * E_PER + pos] = es[i];
}

// ---------------- weight convert ----------------
__global__ void k_convw(const float* __restrict__ pre, const float* __restrict__ post,
                        const float* __restrict__ qW, const float* __restrict__ kW,
                        const float* __restrict__ vW, const float* __restrict__ oW,
                        const float* __restrict__ w1, const float* __restrict__ w2,
                        ushort_t* __restrict__ out) {
    int i = blockIdx.x * 256 + threadIdx.x;
    if (i >= 1310720) return;
    float v;
    if (i < 393216) {                        // qkv col-major
        int z = (i >= 196608) ? 1 : 0;
        int r = i - z * 196608;
        int row = r >> 8, k = r & 255;
        int mat = row >> 8, c = row & 255;
        const float* src = (mat == 0) ? qW : (mat == 1) ? kW : vW;
        v = src[z * 65536 + k * 256 + c];
    } else if (i < 655360) {                 // w1 col-major
        int j = i - 393216; int z = j >> 17, r = j & 131071;
        int n = r >> 8, k = r & 255;
        v = w1[z * 131072 + k * 512 + n];
    } else if (i < 1048576) {                // pre/post/o packed
        int j = i - 655360; int mat = j >> 17;
        int e = j & 131071; int z = e >> 16; int q2 = e & 65535;
        int kc = q2 >> 13, col = (q2 >> 5) & 255, k32 = q2 & 31;
        const float* src = (mat == 0) ? pre : (mat == 1) ? post : oW;
        v = src[z * 65536 + (kc * 32 + k32) * 256 + col];
    } else {                                 // w2 packed
        int j = i - 1048576; int z = j >> 17; int e = j & 131071;
        int kc = e >> 13, col = (e >> 5) & 255, k32 = e & 31;
        v = w2[z * 131072 + (kc * 32 + k32) * 256 + col];
    }
    out[i] = f2bf(v);
}

// pack q/k/v biases -> [2][768]
__global__ void k_packbias(const float* __restrict__ qb, const float* __restrict__ kb,
                           const float* __restrict__ vb, float* __restrict__ out) {
    int i = blockIdx.x * 256 + threadIdx.x;
    if (i >= 1536) return;
    int z = i / 768, c = i % 768;
    int mat = c >> 8, cc = c & 255;
    const float* src = (mat == 0) ? qb : (mat == 1) ? kb : vb;
    out[i] = src[z * 256 + cc];
}

// ---------------- LayerNorm (+optional cs scale) -> bf16 ----------------
__global__ __launch_bounds__(256) void k_ln(const float* __restrict__ h,
                                            const float* __restrict__ g, const float* __restrict__ b,
                                            const float* __restrict__ cs, ushort_t* __restrict__ out) {
    int lane = threadIdx.x & 63;
    int row = blockIdx.x * 4 + (threadIdx.x >> 6);
    int ty = row >= N_PER;
    float4 x = *(const float4*)(h + (size_t)row * HID + lane * 4);
    float s = x.x + x.y + x.z + x.w;
    float q = x.x * x.x + x.y * x.y + x.z * x.z + x.w * x.w;
    for (int m = 1; m < 64; m <<= 1) {
        s += __shfl_xor(s, m, 64);
        q += __shfl_xor(q, m, 64);
    }
    float mean = s * (1.f / 256.f);
    float var = q * (1.f / 256.f) - mean * mean;
    float rs = rsqrtf(var + 1e-5f);
    float sc = cs ? cs[row] : 1.f;
    int c = lane * 4;
    const float* gp = g + ty * HID + c;
    const float* bp = b + ty * HID + c;
    float xv[4] = {x.x, x.y, x.z, x.w};
    ushort4v o;
#pragma unroll
    for (int i = 0; i < 4; i++) {
        float y = ((xv[i] - mean) * rs * gp[i] + bp[i]) * sc;
        o[i] = f2bf(y);
    }
    *(ushort4v*)(out + (size_t)row * HID + c) = o;
}

// ---------------- conv gather (4-wide unrolled) ----------------
__global__ __launch_bounds__(256) void k_gather(const ushort_t* __restrict__ hn,
                                                const int* __restrict__ off, const int* __restrict__ csr,
                                                ushort_t* __restrict__ agg) {
    int lane = threadIdx.x & 63;
    int row = blockIdx.x * 4 + (threadIdx.x >> 6);
    int dt = row >= N_PER;
    int n = row - dt * N_PER;
    int et = 1 - dt;
    int s0 = off[et * (N_PER + 1) + n], s1 = off[et * (N_PER + 1) + n + 1];
    const ushort_t* hb = hn + (size_t)et * N_PER * HID + lane * 4;
    const int* list = csr + et * E_PER;
    float a0 = 0, a1 = 0, a2 = 0, a3 = 0;
    int e = s0;
    for (; e + 4 <= s1; e += 4) {
        int ia = list[e], ib = list[e + 1], ic = list[e + 2], id = list[e + 3];
        ushort4v ua = *(const ushort4v*)(hb + (size_t)ia * HID);
        ushort4v ub = *(const ushort4v*)(hb + (size_t)ib * HID);
        ushort4v uc = *(const ushort4v*)(hb + (size_t)ic * HID);
        ushort4v ud = *(const ushort4v*)(hb + (size_t)id * HID);
        a0 += bf2f(ua[0]) + bf2f(ub[0]) + bf2f(uc[0]) + bf2f(ud[0]);
        a1 += bf2f(ua[1]) + bf2f(ub[1]) + bf2f(uc[1]) + bf2f(ud[1]);
        a2 += bf2f(ua[2]) + bf2f(ub[2]) + bf2f(uc[2]) + bf2f(ud[2]);
        a3 += bf2f(ua[3]) + bf2f(ub[3]) + bf2f(uc[3]) + bf2f(ud[3]);
    }
    for (; e < s1; ++e) {
        int src = list[e];
        ushort4v u = *(const ushort4v*)(hb + (size_t)src * HID);
        a0 += bf2f(u[0]); a1 += bf2f(u[1]); a2 += bf2f(u[2]); a3 += bf2f(u[3]);
    }
    ushort4v o; o[0] = f2bf(a0); o[1] = f2bf(a1); o[2] = f2bf(a2); o[3] = f2bf(a3);
    *(ushort4v*)(agg + ((size_t)et * N_PER + n) * HID + lane * 4) = o;
}

// ---------------- fused edge softmax attention (4-wide, interleaved KV) ----------------
__global__ __launch_bounds__(256) void k_attn(const ushort_t* __restrict__ q,
                                              const ushort_t* __restrict__ kv,
                                              const int* __restrict__ off, const int* __restrict__ csr,
                                              ushort_t* __restrict__ outb) {
    int lane = threadIdx.x & 63;
    int row = blockIdx.x * 4 + (threadIdx.x >> 6);
    int dt = row >= N_PER;
    int n = row - dt * N_PER;
    int et = 1 - dt;
    int s0 = off[et * (N_PER + 1) + n], s1 = off[et * (N_PER + 1) + n + 1];
    ushort4v qu = *(const ushort4v*)(q + (size_t)row * HID + lane * 4);
    float q0 = bf2f(qu[0]), q1 = bf2f(qu[1]), q2 = bf2f(qu[2]), q3 = bf2f(qu[3]);
    const ushort_t* kvb = kv + (size_t)et * N_PER * 512 + lane * 4;
    const int* list = csr + et * E_PER;
    float l = 0.f;
    float O0 = 0, O1 = 0, O2 = 0, O3 = 0;
    int e = s0;
    for (; e + 4 <= s1; e += 4) {
        const ushort_t* p0 = kvb + (size_t)list[e] * 512;
        const ushort_t* p1 = kvb + (size_t)list[e + 1] * 512;
        const ushort_t* p2 = kvb + (size_t)list[e + 2] * 512;
        const ushort_t* p3 = kvb + (size_t)list[e + 3] * 512;
        ushort4v k0 = *(const ushort4v*)p0, v0 = *(const ushort4v*)(p0 + 256);
        ushort4v k1 = *(const ushort4v*)p1, v1 = *(const ushort4v*)(p1 + 256);
        ushort4v k2 = *(const ushort4v*)p2, v2 = *(const ushort4v*)(p2 + 256);
        ushort4v k3 = *(const ushort4v*)p3, v3 = *(const ushort4v*)(p3 + 256);
        float d0 = q0 * bf2f(k0[0]) + q1 * bf2f(k0[1]) + q2 * bf2f(k0[2]) + q3 * bf2f(k0[3]);
        float d1 = q0 * bf2f(k1[0]) + q1 * bf2f(k1[1]) + q2 * bf2f(k1[2]) + q3 * bf2f(k1[3]);
        float d2 = q0 * bf2f(k2[0]) + q1 * bf2f(k2[1]) + q2 * bf2f(k2[2]) + q3 * bf2f(k2[3]);
        float d3 = q0 * bf2f(k3[0]) + q1 * bf2f(k3[1]) + q2 * bf2f(k3[2]) + q3 * bf2f(k3[3]);
        d0 += __shfl_xor(d0, 1, 64); d1 += __shfl_xor(d1, 1, 64);
        d2 += __shfl_xor(d2, 1, 64); d3 += __shfl_xor(d3, 1, 64);
        d0 += __shfl_xor(d0, 2, 64); d1 += __shfl_xor(d1, 2, 64);
        d2 += __shfl_xor(d2, 2, 64); d3 += __shfl_xor(d3, 2, 64);
        d0 += __shfl_xor(d0, 4, 64); d1 += __shfl_xor(d1, 4, 64);
        d2 += __shfl_xor(d2, 4, 64); d3 += __shfl_xor(d3, 4, 64);
        float s0f = fminf(5.f, fmaxf(-5.f, d0 * 0.17677669529663687f));
        float s1f = fminf(5.f, fmaxf(-5.f, d1 * 0.17677669529663687f));
        float s2f = fminf(5.f, fmaxf(-5.f, d2 * 0.17677669529663687f));
        float s3f = fminf(5.f, fmaxf(-5.f, d3 * 0.17677669529663687f));
        float e0 = __expf(s0f), e1 = __expf(s1f), e2 = __expf(s2f), e3 = __expf(s3f);
        l += (e0 + e1) + (e2 + e3);
        O0 += e0 * bf2f(v0[0]) + e1 * bf2f(v1[0]) + e2 * bf2f(v2[0]) + e3 * bf2f(v3[0]);
        O1 += e0 * bf2f(v0[1]) + e1 * bf2f(v1[1]) + e2 * bf2f(v2[1]) + e3 * bf2f(v3[1]);
        O2 += e0 * bf2f(v0[2]) + e1 * bf2f(v1[2]) + e2 * bf2f(v2[2]) + e3 * bf2f(v3[2]);
        O3 += e0 * bf2f(v0[3]) + e1 * bf2f(v1[3]) + e2 * bf2f(v2[3]) + e3 * bf2f(v3[3]);
    }
    for (; e < s1; ++e) {
        const ushort_t* p = kvb + (size_t)list[e] * 512;
        ushort4v ku = *(const ushort4v*)p;
        ushort4v vu = *(const ushort4v*)(p + 256);
        float d = q0 * bf2f(ku[0]) + q1 * bf2f(ku[1]) + q2 * bf2f(ku[2]) + q3 * bf2f(ku[3]);
        d += __shfl_xor(d, 1, 64);
        d += __shfl_xor(d, 2, 64);
        d += __shfl_xor(d, 4, 64);
        float s = fminf(5.f, fmaxf(-5.f, d * 0.17677669529663687f));
        float p2 = __expf(s);
        l += p2;
        O0 += p2 * bf2f(vu[0]); O1 += p2 * bf2f(vu[1]);
        O2 += p2 * bf2f(vu[2]); O3 += p2 * bf2f(vu[3]);
    }
    float inv = (l > 0.f) ? 1.f / l : 0.f;
    ushort4v o;
    o[0] = f2bf(O0 * inv); o[1] = f2bf(O1 * inv); o[2] = f2bf(O2 * inv); o[3] = f2bf(O3 * inv);
    *(ushort4v*)(outb + (size_t)row * HID + lane * 4) = o;
}

// ---------------- full-row conv GEMM + residual + fused LayerNorm (v3) ----------------
// Column-split waves: block = 64 rows x 256 cols, wave w owns ALL 64 rows x cols
// w*64..w*64+63 -> acc[4][4], 16 MFMA per kt from only 4 A + 4 B ds_read_b128
// (v2 was 16 reads: each wave re-read the whole Bs -> LDS-throughput bound).
// A now staged through LDS (shared by waves) with gemm5's XOR swizzle; both
// As and Bs double-buffered, one barrier per kt, global prefetch 1-deep.
// Fused LN needs a cross-wave row reduction: per-wave 64-col partials via
// shfl over ml-lanes -> 2KB LDS scratch -> row stats -> apply. Numerics match
// v2 up to ~1ulp reassociation ((hv-mean)*(rs*sc)*g + b*sc).
template <int KT, bool LN>
__global__ __launch_bounds__(256, 3)
void k_cgemm(const ushort_t* __restrict__ A, long Az,
             const ushort_t* __restrict__ Bpk, long Bz,
             const float* __restrict__ bias,
             const float* __restrict__ base, float* __restrict__ fout, int swapz,
             const float* __restrict__ convscale,
             const float* __restrict__ g, const float* __restrict__ b,
             const float* __restrict__ lncs, ushort_t* __restrict__ hnout) {
    constexpr int K = KT * 32;
    __shared__ __align__(16) ushort_t As[2][64 * 32];    // 2 x 4KB
    __shared__ __align__(16) ushort_t Bs[2][256 * 32];   // 2 x 16KB
    __shared__ float redS[2][64][4];                     // 2KB
    __shared__ float rowM[64], rowP[64], rowS[64];       // 768B
    const int t = threadIdx.x;
    const int lane = t & 63, w = t >> 6;                 // 4 waves
    const int ml = lane & 15, qo = lane >> 4;
    const int z = blockIdx.z;
    const int m0 = blockIdx.x * 64;
    const ushort_t* Ab = A + (long)z * Az;
    const ushort_t* Bp = Bpk + (long)z * Bz;
    const ushort8v z8 = {0, 0, 0, 0, 0, 0, 0, 0};

    // A staging: thread t stages row t>>2, chunk t&3 (8 elems)
    const int sArow = t >> 2, sAch = t & 3;
    const bool aok = (m0 + sArow) < N_PER;
    const long aGb = (long)(m0 + sArow) * K + sAch * 8;
    const int awoff = sArow * 32 + ((sAch ^ (sArow & 3)) << 3);
    // B staging: thread t stages row t, chunks 0..3
    int bwoff[4];
#pragma unroll
    for (int c = 0; c < 4; c++) bwoff[c] = t * 32 + ((c ^ (t & 3)) << 3);

    // MFMA fragment read offsets (swizzle matches writes: row&3 == ml&3)
    const int ro = ((qo ^ (ml & 3)) << 3);
    int aro[4], bro[4];
#pragma unroll
    for (int i = 0; i < 4; i++) {
        aro[i] = (i * 16 + ml) * 32 + ro;
        bro[i] = (w * 64 + i * 16 + ml) * 32 + ro;
    }

    floatx4 acc[4][4];
#pragma unroll
    for (int i = 0; i < 4; i++)
#pragma unroll
        for (int j = 0; j < 4; j++) acc[i][j] = (floatx4){0.f, 0.f, 0.f, 0.f};

    // prologue: stage kt=0
    ushort8v ast = aok ? *(const ushort8v*)(Ab + aGb) : z8;
    ushort8v bst[4];
#pragma unroll
    for (int c = 0; c < 4; c++) bst[c] = *(const ushort8v*)(Bp + t * 32 + c * 8);
    *(ushort8v*)(As[0] + awoff) = ast;
#pragma unroll
    for (int c = 0; c < 4; c++) *(ushort8v*)(Bs[0] + bwoff[c]) = bst[c];
    __syncthreads();

    for (int kt = 0; kt < KT; kt++) {
        const int cur = kt & 1;
        if (kt + 1 < KT) {
            ast = aok ? *(const ushort8v*)(Ab + aGb + (kt + 1) * 32) : z8;
            const ushort_t* gs = Bp + (long)(kt + 1) * 8192;
#pragma unroll
            for (int c = 0; c < 4; c++) bst[c] = *(const ushort8v*)(gs + t * 32 + c * 8);
        }
        bf16x8 af[4], bf[4];
#pragma unroll
        for (int i = 0; i < 4; i++) {
            af[i] = *(const bf16x8*)(As[cur] + aro[i]);
            bf[i] = *(const bf16x8*)(Bs[cur] + bro[i]);
        }
#pragma unroll
        for (int i = 0; i < 4; i++)
#pragma unroll
            for (int j = 0; j < 4; j++)
                acc[i][j] = __builtin_amdgcn_mfma_f32_16x16x32_bf16(af[i], bf[j], acc[i][j], 0, 0, 0);
        if (kt + 1 < KT) {
            *(ushort8v*)(As[cur ^ 1] + awoff) = ast;
#pragma unroll
            for (int c = 0; c < 4; c++) *(ushort8v*)(Bs[cur ^ 1] + bwoff[c]) = bst[c];
        }
        __syncthreads();
    }

    const int zo = swapz ? 1 - z : z;
    float csv[4][4];
#pragma unroll
    for (int i = 0; i < 4; i++)
#pragma unroll
        for (int r = 0; r < 4; r++) {
            int m = m0 + i * 16 + qo * 4 + r;
            csv[i][r] = (convscale && m < N_PER) ? convscale[z * N_PER + m] : 1.f;
        }
    float biasv[4], gvv[4], bvv[4];
#pragma unroll
    for (int j = 0; j < 4; j++) {
        int col = w * 64 + j * 16 + ml;
        biasv[j] = bias[z * 256 + col];
        if (LN) { gvv[j] = g[zo * 256 + col]; bvv[j] = b[zo * 256 + col]; }
    }

    float s1[4][4], s2[4][4];
#pragma unroll
    for (int i = 0; i < 4; i++)
#pragma unroll
        for (int r = 0; r < 4; r++) { s1[i][r] = 0.f; s2[i][r] = 0.f; }

#pragma unroll
    for (int i = 0; i < 4; i++) {
#pragma unroll
        for (int r = 0; r < 4; r++) {
            int m = m0 + i * 16 + qo * 4 + r;
            if (m >= N_PER) continue;
            size_t rowb = ((size_t)zo * N_PER + m) * 256 + w * 64 + ml;
#pragma unroll
            for (int j = 0; j < 4; j++) {
                float vv = acc[i][j][r] * csv[i][r] + biasv[j];
                float hv = base[rowb + j * 16] + vv;
                fout[rowb + j * 16] = hv;
                acc[i][j][r] = hv;
                if (LN) { s1[i][r] += hv; s2[i][r] += hv * hv; }
            }
        }
    }
    if (LN) {
#pragma unroll
        for (int i = 0; i < 4; i++)
#pragma unroll
            for (int r = 0; r < 4; r++) {
#pragma unroll
                for (int mm = 1; mm < 16; mm <<= 1) {
                    s1[i][r] += __shfl_xor(s1[i][r], mm, 64);
                    s2[i][r] += __shfl_xor(s2[i][r], mm, 64);
                }
            }
        if (ml == 0) {
#pragma unroll
            for (int i = 0; i < 4; i++)
#pragma unroll
                for (int r = 0; r < 4; r++) {
                    int row = i * 16 + qo * 4 + r;
                    redS[0][row][w] = s1[i][r];
                    redS[1][row][w] = s2[i][r];
                }
        }
        __syncthreads();
        if (t < 64) {
            float a1 = redS[0][t][0] + redS[0][t][1] + redS[0][t][2] + redS[0][t][3];
            float a2 = redS[1][t][0] + redS[1][t][1] + redS[1][t][2] + redS[1][t][3];
            float mean = a1 * (1.f / 256.f);
            float var = a2 * (1.f / 256.f) - mean * mean;
            float rs = rsqrtf(var + 1e-5f);
            int m = m0 + t;
            float sc = (lncs && m < N_PER) ? lncs[zo * N_PER + m] : 1.f;
            rowM[t] = mean; rowP[t] = rs * sc; rowS[t] = sc;
        }
        __syncthreads();
#pragma unroll
        for (int i = 0; i < 4; i++) {
#pragma unroll
            for (int r = 0; r < 4; r++) {
                int row = i * 16 + qo * 4 + r;
                int m = m0 + row;
                if (m >= N_PER) continue;
                float mean = rowM[row], P = rowP[row], S = rowS[row];
                size_t rowb = ((size_t)zo * N_PER + m) * 256 + w * 64 + ml;
#pragma unroll
                for (int j = 0; j < 4; j++) {
                    float y = (acc[i][j][r] - mean) * P * gvv[j] + bvv[j] * S;
                    hnout[rowb + j * 16] = f2bf(y);
                }
            }
        }
    }
}

// ---------------- m97-style 128x128 dbuf GEMM (qkv / ffn1, bf16 out) ----------------
// MODE 1: q -> bout[0:25.6MB], K/V interleaved -> bout+2*N_PER*256 as [z][m][512]
// MODE 2: ffn1 bf16 gelu, row stride 512
template <int MODE, int KT>
__global__ __launch_bounds__(256, 3)
void k_gemm5(const ushort_t* __restrict__ A, long Az,
             const ushort_t* __restrict__ BT, long Bz,
             const float* __restrict__ bias,
             ushort_t* __restrict__ bout) {
    constexpr int K = KT * 32;
    constexpr int BCOLS = (MODE == 1) ? 768 : 512;
    constexpr int NY = (MODE == 1) ? 6 : 4;
    constexpr int CHUNK = 196 * NY / 8;
    __shared__ __align__(16) ushort_t As[2][128 * 32];
    __shared__ __align__(16) ushort_t Bs[2][128 * 32];
    const int t = threadIdx.x;
    const int lane = t & 63, w = t >> 6;
    const int wm = w & 1, wn = w >> 1;
    const int ml = lane & 15, qo = lane >> 4;
    const int z = blockIdx.z;

    const int lin2 = blockIdx.y * 196 + blockIdx.x;
    const int nid = (lin2 & 7) * CHUNK + (lin2 >> 3);
    const int m0 = (nid / NY) * 128, n0 = (nid % NY) * 128;

    const ushort_t* Ab = A + (long)z * Az;
    const ushort_t* Bb = BT + (long)z * Bz;
    const ushort8v z8 = {0, 0, 0, 0, 0, 0, 0, 0};

    const int srow = t >> 1;
    const int sc0 = (t & 1) * 2;
    const int garow = m0 + srow;
    const long aGb = (long)garow * K + sc0 * 8;
    const long bGb = (long)(n0 + srow) * K + sc0 * 8;
    const int sw0 = srow * 32 + ((sc0 ^ (srow & 3)) << 3);
    const int sw1 = srow * 32 + (((sc0 + 1) ^ (srow & 3)) << 3);
    const bool aok = garow < N_PER;

    int aro[4], bro[4];
#pragma unroll
    for (int i = 0; i < 4; i++) {
        aro[i] = (wm * 64 + i * 16 + ml) * 32 + ((qo ^ (ml & 3)) << 3);
        bro[i] = (wn * 64 + i * 16 + ml) * 32 + ((qo ^ (ml & 3)) << 3);
    }

    floatx4 acc[4][4];
#pragma unroll
    for (int i = 0; i < 4; i++)
#pragma unroll
        for (int j = 0; j < 4; j++) acc[i][j] = (floatx4){0.f, 0.f, 0.f, 0.f};

    {
        ushort8v a0 = aok ? *(const ushort8v*)(Ab + aGb) : z8;
        ushort8v a1 = aok ? *(const ushort8v*)(Ab + aGb + 8) : z8;
        ushort8v b0 = *(const ushort8v*)(Bb + bGb);
        ushort8v b1 = *(const ushort8v*)(Bb + bGb + 8);
        *(ushort8v*)(As[0] + sw0) = a0;
        *(ushort8v*)(As[0] + sw1) = a1;
        *(ushort8v*)(Bs[0] + sw0) = b0;
        *(ushort8v*)(Bs[0] + sw1) = b1;
    }

#pragma unroll
    for (int kt = 0; kt < KT; kt++) {
        __syncthreads();
        const int cur = kt & 1;
        bf16x8 af[4], bf[4];
#pragma unroll
        for (int i = 0; i < 4; i++) {
            af[i] = *(const bf16x8*)(As[cur] + aro[i]);
            bf[i] = *(const bf16x8*)(Bs[cur] + bro[i]);
        }
        if (kt + 1 < KT) {
            const int nk = (kt + 1) * 32;
            ushort8v a0 = aok ? *(const ushort8v*)(Ab + aGb + nk) : z8;
            ushort8v a1 = aok ? *(const ushort8v*)(Ab + aGb + nk + 8) : z8;
            ushort8v b0 = *(const ushort8v*)(Bb + bGb + nk);
            ushort8v b1 = *(const ushort8v*)(Bb + bGb + nk + 8);
            const int nb = cur ^ 1;
            *(ushort8v*)(As[nb] + sw0) = a0;
            *(ushort8v*)(As[nb] + sw1) = a1;
            *(ushort8v*)(Bs[nb] + sw0) = b0;
            *(ushort8v*)(Bs[nb] + sw1) = b1;
        }
#pragma unroll
        for (int i = 0; i < 4; i++)
#pragma unroll
            for (int j = 0; j < 4; j++)
                acc[i][j] = __builtin_amdgcn_mfma_f32_16x16x32_bf16(af[i], bf[j], acc[i][j], 0, 0, 0);
    }

#pragma unroll
    for (int i = 0; i < 4; i++) {
        int mb = m0 + wm * 64 + i * 16 + qo * 4;
#pragma unroll
        for (int j = 0; j < 4; j++) {
            int col = n0 + wn * 64 + j * 16 + ml;
            float bv = bias[z * BCOLS + col];
#pragma unroll
            for (int r = 0; r < 4; r++) {
                int m = mb + r;
                if (m >= N_PER) continue;
                float vv = acc[i][j][r] + bv;
                if (MODE == 2) {
                    vv = fast_gelu(vv);
                    bout[((size_t)z * N_PER + m) * 512 + col] = f2bf(vv);
                } else {
                    int mat = col >> 8, cc = col & 255;
                    if (mat == 0)
                        bout[((size_t)z * N_PER + m) * 256 + cc] = f2bf(vv);
                    else
                        bout[(size_t)2 * N_PER * 256 +
                             ((size_t)z * N_PER + m) * 512 + (size_t)(mat - 1) * 256 + cc] = f2bf(vv);
                }
            }
        }
    }
}

extern "C" void kernel_launch(void* const* d_in, const int* in_sizes, int n_in,
                              void* d_out, int out_size, void* d_ws, size_t ws_size,
                              hipStream_t stream) {
    const float* h_in   = (const float*)d_in[0];
    const int*   e_src  = (const int*)d_in[1];
    const int*   e_dst  = (const int*)d_in[2];
    const float* pre_W  = (const float*)d_in[3];
    const float* pre_b  = (const float*)d_in[4];
    const float* post_W = (const float*)d_in[5];
    const float* post_b = (const float*)d_in[6];
    const float* q_W    = (const float*)d_in[7];
    const float* q_b    = (const float*)d_in[8];
    const float* k_W    = (const float*)d_in[9];
    const float* k_b    = (const float*)d_in[10];
    const float* v_W    = (const float*)d_in[11];
    const float* v_b    = (const float*)d_in[12];
    const float* o_W    = (const float*)d_in[13];
    const float* o_b    = (const float*)d_in[14];
    const float* ffn_W1 = (const float*)d_in[15];
    const float* ffn_b1 = (const float*)d_in[16];
    const float* ffn_W2 = (const float*)d_in[17];
    const float* ffn_b2 = (const float*)d_in[18];
    const float* ln_pre_g  = (const float*)d_in[19];
    const float* ln_pre_b  = (const float*)d_in[20];
    const float* ln_attn_g = (const float*)d_in[21];
    const float* ln_attn_b = (const float*)d_in[22];
    const float* ln_post_g = (const float*)d_in[23];
    const float* ln_post_b = (const float*)d_in[24];
    const float* ln_ffn_g  = (const float*)d_in[25];
    const float* ln_ffn_b  = (const float*)d_in[26];

    float* hout = (float*)d_out;
    char* ws = (char*)d_ws;

    const long AzH = (long)N_PER * HID;

    // workspace layout (bytes)
    ushort_t* hn    = (ushort_t*)(ws + 0);              // 25.6 MB bf16 [2][25000][256]
    ushort_t* qkv   = (ushort_t*)(ws + 25600000);       // q 25.6MB; kv 51.2MB @51.2M
    ushort_t* fb    = (ushort_t*)(ws + 25600000);       // 51.2 MB (aliases q+kv-front; dead by FFN)
    ushort_t* agg   = (ushort_t*)(ws + 102400000);      // 25.6 MB
    ushort_t* wT    = (ushort_t*)(ws + 128000000);      // 2.62 MB
    float* qkvbias  = (float*)(ws + 130621440);
    float* cs       = (float*)(ws + 130627584);
    float* cd       = (float*)(ws + 130827584);
    int* cnt_s      = (int*)(ws + 131027584);
    int* cnt_d      = (int*)(ws + 131227584);
    int* off        = (int*)(ws + 131427584);
    int* cur        = (int*)(ws + 131627592);
    int* csr        = (int*)(ws + 131827592);

    const ushort_t* qkvWT = wT;
    const ushort_t* w1T   = wT + 393216;
    const ushort_t* preP  = wT + 655360;
    const ushort_t* postP = wT + 786432;
    const ushort_t* oP    = wT + 917504;
    const ushort_t* w2P   = wT + 1048576;
    ushort_t* qb  = qkv;                       // [2][25000][256]
    ushort_t* kvb = qkv + 2 * AzH;             // [2][25000][512] K|V interleaved

    hipMemsetAsync(cnt_s, 0, 400000, stream);

    k_convw<<<5120, 256, 0, stream>>>(pre_W, post_W, q_W, k_W, v_W, o_W, ffn_W1, ffn_W2, wT);
    k_packbias<<<6, 256, 0, stream>>>(q_b, k_b, v_b, qkvbias);
    k_count<<<1563, 256, 0, stream>>>(e_src, e_dst, cnt_s, cnt_d);
    k_scale<<<196, 256, 0, stream>>>(cnt_s, cnt_d, cs, cd);
    k_scan<<<2, 1024, 0, stream>>>(cnt_d, off, cur);
    k_fill<<<1563, 256, 0, stream>>>(e_src, e_dst, cur, csr);

    // ---- stage 1: pre hetero-conv (+fused LN_attn) ----
    k_ln<<<12500, 256, 0, stream>>>(h_in, ln_pre_g, ln_pre_b, cs, hn);
    k_gather<<<12500, 256, 0, stream>>>(hn, off, csr, agg);
    k_cgemm<8, true><<<dim3(391, 1, 2), 256, 0, stream>>>(
        agg, AzH, preP, 65536, pre_b, h_in, hout, 1, cd,
        ln_attn_g, ln_attn_b, (const float*)nullptr, hn);

    // ---- stage 2: sparse attention (+fused LN_post w/ cs) ----
    k_gemm5<1, 8><<<dim3(196, 6, 2), 256, 0, stream>>>(hn, AzH, qkvWT, 196608, qkvbias, qkv);
    k_attn<<<12500, 256, 0, stream>>>(qb, kvb, off, csr, agg);
    k_cgemm<8, true><<<dim3(391, 1, 2), 256, 0, stream>>>(
        agg, AzH, oP, 65536, o_b, hout, hout, 0, (const float*)nullptr,
        ln_post_g, ln_post_b, cs, hn);

    // ---- stage 3: post hetero-conv (+fused LN_ffn) ----
    k_gather<<<12500, 256, 0, stream>>>(hn, off, csr, agg);
    k_cgemm<8, true><<<dim3(391, 1, 2), 256, 0, stream>>>(
        agg, AzH, postP, 65536, post_b, hout, hout, 1, cd,
        ln_ffn_g, ln_ffn_b, (const float*)nullptr, hn);

    // ---- stage 4: FFN ----
    k_gemm5<2, 8><<<dim3(196, 4, 2), 256, 0, stream>>>(hn, AzH, w1T, 131072, ffn_b1, fb);
    k_cgemm<16, false><<<dim3(391, 1, 2), 256, 0, stream>>>(
        fb, (long)N_PER * 512, w2P, 131072, ffn_b2, hout, hout, 0, (const float*)nullptr,
        (const float*)nullptr, (const float*)nullptr, (const float*)nullptr, (ushort_t*)nullptr);
}

// Round 13
// 619.965 us; speedup vs baseline: 1.0461x; 1.0461x over previous
//
// build-salt: r13-revert-to-best (round-6/11 source, 618.97/619.65us measured)
#include <hip/hip_runtime.h>
#include <math.h>

#define N_PER 25000
#define HID 256
#define E_PER 200000

typedef unsigned short ushort_t;
typedef __attribute__((ext_vector_type(8))) unsigned short ushort8v;
typedef __attribute__((ext_vector_type(4))) unsigned short ushort4v;
typedef __attribute__((ext_vector_type(8))) __bf16 bf16x8;
typedef __attribute__((ext_vector_type(4))) float floatx4;

__device__ __forceinline__ float bf2f(unsigned short u) {
    union { unsigned int i; float f; } c; c.i = ((unsigned int)u) << 16; return c.f;
}
__device__ __forceinline__ unsigned short f2bf(float f) {
    union { float f; unsigned int i; } c; c.f = f;
    unsigned int i = c.i;
    return (unsigned short)((i + 0x7FFFu + ((i >> 16) & 1u)) >> 16);
}

// fast GELU: x * sigmoid(1.5957691 * (x + 0.044715 x^3))  (tanh-form approx)
__device__ __forceinline__ float fast_gelu(float x) {
    float u = 1.595769122f * x * (1.f + 0.044715f * x * x);
    float e = __expf(-u);
    return x * __builtin_amdgcn_rcpf(1.f + e);
}

// ---------------- degree counting ----------------
__global__ void k_count(const int* __restrict__ es, const int* __restrict__ ed,
                        int* __restrict__ cnt_s, int* __restrict__ cnt_d) {
    int i = blockIdx.x * 256 + threadIdx.x;
    if (i >= 2 * E_PER) return;
    int et = i / E_PER;
    atomicAdd(&cnt_s[et * N_PER + es[i]], 1);
    atomicAdd(&cnt_d[et * N_PER + ed[i]], 1);
}

__global__ void k_scale(const int* __restrict__ cnt_s, const int* __restrict__ cnt_d,
                        float* __restrict__ cs, float* __restrict__ cd) {
    int i = blockIdx.x * 256 + threadIdx.x;
    if (i >= 2 * N_PER) return;
    cs[i] = rsqrtf(fmaxf((float)cnt_s[i], 1.f));
    cd[i] = rsqrtf(fmaxf((float)cnt_d[i], 1.f));
}

// ---------------- CSR build: scan + fill ----------------
__global__ __launch_bounds__(1024) void k_scan(const int* __restrict__ cnt,
                                               int* __restrict__ off, int* __restrict__ cur) {
    int et = blockIdx.x, t = threadIdx.x;
    const int* c = cnt + et * N_PER;
    int loc[25]; int tot = 0;
#pragma unroll
    for (int j = 0; j < 25; j++) {
        int idx = t * 25 + j;
        int v = (idx < N_PER) ? c[idx] : 0;
        loc[j] = tot; tot += v;
    }
    __shared__ int sb[1024];
    sb[t] = tot; __syncthreads();
    for (int d = 1; d < 1024; d <<= 1) {
        int v = (t >= d) ? sb[t - d] : 0;
        __syncthreads();
        sb[t] += v;
        __syncthreads();
    }
    int base = sb[t] - tot;
#pragma unroll
    for (int j = 0; j < 25; j++) {
        int idx = t * 25 + j;
        if (idx <= N_PER) {
            int val = base + loc[j];
            off[et * (N_PER + 1) + idx] = val;
            if (idx < N_PER) cur[et * N_PER + idx] = val;
        }
    }
}

__global__ void k_fill(const int* __restrict__ es, const int* __restrict__ ed,
                       int* __restrict__ cur, int* __restrict__ csr) {
    int i = blockIdx.x * 256 + threadIdx.x;
    if (i >= 2 * E_PER) return;
    int et = i / E_PER;
    int d = ed[i];
    int pos = atomicAdd(&cur[et * N_PER + d], 1);
    csr[et * E_PER + pos] = es[i];
}

// ---------------- weight convert ----------------
__global__ void k_convw(const float* __restrict__ pre, const float* __restrict__ post,
                        const float* __restrict__ qW, const float* __restrict__ kW,
                        const float* __restrict__ vW, const float* __restrict__ oW,
                        const float* __restrict__ w1, const float* __restrict__ w2,
                        ushort_t* __restrict__ out) {
    int i = blockIdx.x * 256 + threadIdx.x;
    if (i >= 1310720) return;
    float v;
    if (i < 393216) {                        // qkv col-major
        int z = (i >= 196608) ? 1 : 0;
        int r = i - z * 196608;
        int row = r >> 8, k = r & 255;
        int mat = row >> 8, c = row & 255;
        const float* src = (mat == 0) ? qW : (mat == 1) ? kW : vW;
        v = src[z * 65536 + k * 256 + c];
    } else if (i < 655360) {                 // w1 col-major
        int j = i - 393216; int z = j >> 17, r = j & 131071;
        int n = r >> 8, k = r & 255;
        v = w1[z * 131072 + k * 512 + n];
    } else if (i < 1048576) {                // pre/post/o packed
        int j = i - 655360; int mat = j >> 17;
        int e = j & 131071; int z = e >> 16; int q2 = e & 65535;
        int kc = q2 >> 13, col = (q2 >> 5) & 255, k32 = q2 & 31;
        const float* src = (mat == 0) ? pre : (mat == 1) ? post : oW;
        v = src[z * 65536 + (kc * 32 + k32) * 256 + col];
    } else {                                 // w2 packed
        int j = i - 1048576; int z = j >> 17; int e = j & 131071;
        int kc = e >> 13, col = (e >> 5) & 255, k32 = e & 31;
        v = w2[z * 131072 + (kc * 32 + k32) * 256 + col];
    }
    out[i] = f2bf(v);
}

// pack q/k/v biases -> [2][768]
__global__ void k_packbias(const float* __restrict__ qb, const float* __restrict__ kb,
                           const float* __restrict__ vb, float* __restrict__ out) {
    int i = blockIdx.x * 256 + threadIdx.x;
    if (i >= 1536) return;
    int z = i / 768, c = i % 768;
    int mat = c >> 8, cc = c & 255;
    const float* src = (mat == 0) ? qb : (mat == 1) ? kb : vb;
    out[i] = src[z * 256 + cc];
}

// ---------------- LayerNorm (+optional cs scale) -> bf16 ----------------
__global__ __launch_bounds__(256) void k_ln(const float* __restrict__ h,
                                            const float* __restrict__ g, const float* __restrict__ b,
                                            const float* __restrict__ cs, ushort_t* __restrict__ out) {
    int lane = threadIdx.x & 63;
    int row = blockIdx.x * 4 + (threadIdx.x >> 6);
    int ty = row >= N_PER;
    float4 x = *(const float4*)(h + (size_t)row * HID + lane * 4);
    float s = x.x + x.y + x.z + x.w;
    float q = x.x * x.x + x.y * x.y + x.z * x.z + x.w * x.w;
    for (int m = 1; m < 64; m <<= 1) {
        s += __shfl_xor(s, m, 64);
        q += __shfl_xor(q, m, 64);
    }
    float mean = s * (1.f / 256.f);
    float var = q * (1.f / 256.f) - mean * mean;
    float rs = rsqrtf(var + 1e-5f);
    float sc = cs ? cs[row] : 1.f;
    int c = lane * 4;
    const float* gp = g + ty * HID + c;
    const float* bp = b + ty * HID + c;
    float xv[4] = {x.x, x.y, x.z, x.w};
    ushort4v o;
#pragma unroll
    for (int i = 0; i < 4; i++) {
        float y = ((xv[i] - mean) * rs * gp[i] + bp[i]) * sc;
        o[i] = f2bf(y);
    }
    *(ushort4v*)(out + (size_t)row * HID + c) = o;
}

// ---------------- conv gather (4-wide unrolled) ----------------
__global__ __launch_bounds__(256) void k_gather(const ushort_t* __restrict__ hn,
                                                const int* __restrict__ off, const int* __restrict__ csr,
                                                ushort_t* __restrict__ agg) {
    int lane = threadIdx.x & 63;
    int row = blockIdx.x * 4 + (threadIdx.x >> 6);
    int dt = row >= N_PER;
    int n = row - dt * N_PER;
    int et = 1 - dt;
    int s0 = off[et * (N_PER + 1) + n], s1 = off[et * (N_PER + 1) + n + 1];
    const ushort_t* hb = hn + (size_t)et * N_PER * HID + lane * 4;
    const int* list = csr + et * E_PER;
    float a0 = 0, a1 = 0, a2 = 0, a3 = 0;
    int e = s0;
    for (; e + 4 <= s1; e += 4) {
        int ia = list[e], ib = list[e + 1], ic = list[e + 2], id = list[e + 3];
        ushort4v ua = *(const ushort4v*)(hb + (size_t)ia * HID);
        ushort4v ub = *(const ushort4v*)(hb + (size_t)ib * HID);
        ushort4v uc = *(const ushort4v*)(hb + (size_t)ic * HID);
        ushort4v ud = *(const ushort4v*)(hb + (size_t)id * HID);
        a0 += bf2f(ua[0]) + bf2f(ub[0]) + bf2f(uc[0]) + bf2f(ud[0]);
        a1 += bf2f(ua[1]) + bf2f(ub[1]) + bf2f(uc[1]) + bf2f(ud[1]);
        a2 += bf2f(ua[2]) + bf2f(ub[2]) + bf2f(uc[2]) + bf2f(ud[2]);
        a3 += bf2f(ua[3]) + bf2f(ub[3]) + bf2f(uc[3]) + bf2f(ud[3]);
    }
    for (; e < s1; ++e) {
        int src = list[e];
        ushort4v u = *(const ushort4v*)(hb + (size_t)src * HID);
        a0 += bf2f(u[0]); a1 += bf2f(u[1]); a2 += bf2f(u[2]); a3 += bf2f(u[3]);
    }
    ushort4v o; o[0] = f2bf(a0); o[1] = f2bf(a1); o[2] = f2bf(a2); o[3] = f2bf(a3);
    *(ushort4v*)(agg + ((size_t)et * N_PER + n) * HID + lane * 4) = o;
}

// ---------------- fused edge softmax attention (4-wide, interleaved KV) ----------------
__global__ __launch_bounds__(256) void k_attn(const ushort_t* __restrict__ q,
                                              const ushort_t* __restrict__ kv,
                                              const int* __restrict__ off, const int* __restrict__ csr,
                                              ushort_t* __restrict__ outb) {
    int lane = threadIdx.x & 63;
    int row = blockIdx.x * 4 + (threadIdx.x >> 6);
    int dt = row >= N_PER;
    int n = row - dt * N_PER;
    int et = 1 - dt;
    int s0 = off[et * (N_PER + 1) + n], s1 = off[et * (N_PER + 1) + n + 1];
    ushort4v qu = *(const ushort4v*)(q + (size_t)row * HID + lane * 4);
    float q0 = bf2f(qu[0]), q1 = bf2f(qu[1]), q2 = bf2f(qu[2]), q3 = bf2f(qu[3]);
    const ushort_t* kvb = kv + (size_t)et * N_PER * 512 + lane * 4;
    const int* list = csr + et * E_PER;
    float l = 0.f;
    float O0 = 0, O1 = 0, O2 = 0, O3 = 0;
    int e = s0;
    for (; e + 4 <= s1; e += 4) {
        const ushort_t* p0 = kvb + (size_t)list[e] * 512;
        const ushort_t* p1 = kvb + (size_t)list[e + 1] * 512;
        const ushort_t* p2 = kvb + (size_t)list[e + 2] * 512;
        const ushort_t* p3 = kvb + (size_t)list[e + 3] * 512;
        ushort4v k0 = *(const ushort4v*)p0, v0 = *(const ushort4v*)(p0 + 256);
        ushort4v k1 = *(const ushort4v*)p1, v1 = *(const ushort4v*)(p1 + 256);
        ushort4v k2 = *(const ushort4v*)p2, v2 = *(const ushort4v*)(p2 + 256);
        ushort4v k3 = *(const ushort4v*)p3, v3 = *(const ushort4v*)(p3 + 256);
        float d0 = q0 * bf2f(k0[0]) + q1 * bf2f(k0[1]) + q2 * bf2f(k0[2]) + q3 * bf2f(k0[3]);
        float d1 = q0 * bf2f(k1[0]) + q1 * bf2f(k1[1]) + q2 * bf2f(k1[2]) + q3 * bf2f(k1[3]);
        float d2 = q0 * bf2f(k2[0]) + q1 * bf2f(k2[1]) + q2 * bf2f(k2[2]) + q3 * bf2f(k2[3]);
        float d3 = q0 * bf2f(k3[0]) + q1 * bf2f(k3[1]) + q2 * bf2f(k3[2]) + q3 * bf2f(k3[3]);
        d0 += __shfl_xor(d0, 1, 64); d1 += __shfl_xor(d1, 1, 64);
        d2 += __shfl_xor(d2, 1, 64); d3 += __shfl_xor(d3, 1, 64);
        d0 += __shfl_xor(d0, 2, 64); d1 += __shfl_xor(d1, 2, 64);
        d2 += __shfl_xor(d2, 2, 64); d3 += __shfl_xor(d3, 2, 64);
        d0 += __shfl_xor(d0, 4, 64); d1 += __shfl_xor(d1, 4, 64);
        d2 += __shfl_xor(d2, 4, 64); d3 += __shfl_xor(d3, 4, 64);
        float s0f = fminf(5.f, fmaxf(-5.f, d0 * 0.17677669529663687f));
        float s1f = fminf(5.f, fmaxf(-5.f, d1 * 0.17677669529663687f));
        float s2f = fminf(5.f, fmaxf(-5.f, d2 * 0.17677669529663687f));
        float s3f = fminf(5.f, fmaxf(-5.f, d3 * 0.17677669529663687f));
        float e0 = __expf(s0f), e1 = __expf(s1f), e2 = __expf(s2f), e3 = __expf(s3f);
        l += (e0 + e1) + (e2 + e3);
        O0 += e0 * bf2f(v0[0]) + e1 * bf2f(v1[0]) + e2 * bf2f(v2[0]) + e3 * bf2f(v3[0]);
        O1 += e0 * bf2f(v0[1]) + e1 * bf2f(v1[1]) + e2 * bf2f(v2[1]) + e3 * bf2f(v3[1]);
        O2 += e0 * bf2f(v0[2]) + e1 * bf2f(v1[2]) + e2 * bf2f(v2[2]) + e3 * bf2f(v3[2]);
        O3 += e0 * bf2f(v0[3]) + e1 * bf2f(v1[3]) + e2 * bf2f(v2[3]) + e3 * bf2f(v3[3]);
    }
    for (; e < s1; ++e) {
        const ushort_t* p = kvb + (size_t)list[e] * 512;
        ushort4v ku = *(const ushort4v*)p;
        ushort4v vu = *(const ushort4v*)(p + 256);
        float d = q0 * bf2f(ku[0]) + q1 * bf2f(ku[1]) + q2 * bf2f(ku[2]) + q3 * bf2f(ku[3]);
        d += __shfl_xor(d, 1, 64);
        d += __shfl_xor(d, 2, 64);
        d += __shfl_xor(d, 4, 64);
        float s = fminf(5.f, fmaxf(-5.f, d * 0.17677669529663687f));
        float p2 = __expf(s);
        l += p2;
        O0 += p2 * bf2f(vu[0]); O1 += p2 * bf2f(vu[1]);
        O2 += p2 * bf2f(vu[2]); O3 += p2 * bf2f(vu[3]);
    }
    float inv = (l > 0.f) ? 1.f / l : 0.f;
    ushort4v o;
    o[0] = f2bf(O0 * inv); o[1] = f2bf(O1 * inv); o[2] = f2bf(O2 * inv); o[3] = f2bf(O3 * inv);
    *(ushort4v*)(outb + (size_t)row * HID + lane * 4) = o;
}

// ---------------- full-row conv GEMM + residual + fused LayerNorm (v2) ----------------
// 64 rows x 256 cols per block, 256 threads = 4 waves; grid 391x2 -> ~3 blocks/CU.
// Bs double-buffered, one barrier per kt; A 1-deep prefetch; Bs XOR swizzle
// ((col>>1)&3)<<4 on both sides kills the 8-way ds_read bank conflict.
// (v3 column-split with A-through-LDS was tried: 648us vs 619 -- the extra
// staging round-trip cost more than the saved ds_reads. v2 is the keeper.)
template <int KT, bool LN>
__global__ __launch_bounds__(256, 3)
void k_cgemm(const ushort_t* __restrict__ A, long Az,
             const ushort_t* __restrict__ Bpk, long Bz,
             const float* __restrict__ bias,
             const float* __restrict__ base, float* __restrict__ fout, int swapz,
             const float* __restrict__ convscale,
             const float* __restrict__ g, const float* __restrict__ b,
             const float* __restrict__ lncs, ushort_t* __restrict__ hnout) {
    constexpr int K = KT * 32;
    __shared__ __align__(16) ushort_t Bs[2][256 * 32];   // 2 x 16KB
    const int t = threadIdx.x;
    const int lane = t & 63, w = t >> 6;                 // 4 waves
    const int ml = lane & 15, qo = lane >> 4;
    const int z = blockIdx.z;
    const int m0 = blockIdx.x * 64;
    const ushort_t* Ab = A + (long)z * Az;
    const ushort_t* Bp = Bpk + (long)z * Bz;
    const ushort8v z8 = {0, 0, 0, 0, 0, 0, 0, 0};

    const int arow = m0 + w * 16 + ml;
    const bool aok = arow < N_PER;
    const long abase = (long)arow * K + qo * 8;

    int woff[4];
#pragma unroll
    for (int c = 0; c < 4; c++) {
        int u = t * 8 + c * 2048;
        int col = u >> 5;
        woff[c] = u * 2 ^ (((col >> 1) & 3) << 4);
    }
    const int rbase = ml * 64 + ((qo << 4) ^ (((ml >> 1) & 3) << 4));

    floatx4 acc[16];
#pragma unroll
    for (int j = 0; j < 16; j++) acc[j] = (floatx4){0.f, 0.f, 0.f, 0.f};

    ushort8v bst[4];
#pragma unroll
    for (int c = 0; c < 4; c++) bst[c] = *(const ushort8v*)(Bp + t * 8 + c * 2048);
    ushort8v aNext = aok ? *(const ushort8v*)(Ab + abase) : z8;
#pragma unroll
    for (int c = 0; c < 4; c++) *(ushort8v*)((char*)Bs[0] + woff[c]) = bst[c];
    __syncthreads();

    for (int kt = 0; kt < KT; kt++) {
        const int cur = kt & 1;
        ushort8v aCur = aNext;
        if (kt + 1 < KT) {
            const ushort_t* gs = Bp + (long)(kt + 1) * 8192;
#pragma unroll
            for (int c = 0; c < 4; c++) bst[c] = *(const ushort8v*)(gs + t * 8 + c * 2048);
            aNext = aok ? *(const ushort8v*)(Ab + abase + (kt + 1) * 32) : z8;
        }
#pragma unroll
        for (int j = 0; j < 16; j++) {
            bf16x8 bfr = *(const bf16x8*)((const char*)Bs[cur] + j * 1024 + rbase);
            acc[j] = __builtin_amdgcn_mfma_f32_16x16x32_bf16(*(bf16x8*)&aCur, bfr, acc[j], 0, 0, 0);
        }
        if (kt + 1 < KT) {
#pragma unroll
            for (int c = 0; c < 4; c++) *(ushort8v*)((char*)Bs[cur ^ 1] + woff[c]) = bst[c];
        }
        __syncthreads();
    }

    const int zo = swapz ? 1 - z : z;
    const int mb = m0 + w * 16 + qo * 4;
    float cs4[4];
#pragma unroll
    for (int r = 0; r < 4; r++)
        cs4[r] = (convscale && mb + r < N_PER) ? convscale[z * N_PER + mb + r] : 1.f;
    float biasv[16], gv[16], bv[16];
#pragma unroll
    for (int j = 0; j < 16; j++) {
        int col = j * 16 + ml;
        biasv[j] = bias[z * 256 + col];
        if (LN) { gv[j] = g[zo * 256 + col]; bv[j] = b[zo * 256 + col]; }
    }

    float s1[4] = {0, 0, 0, 0}, s2[4] = {0, 0, 0, 0};
#pragma unroll
    for (int r = 0; r < 4; r++) {
        int m = mb + r;
        if (m >= N_PER) continue;
        size_t rowb = ((size_t)zo * N_PER + m) * 256 + ml;
#pragma unroll
        for (int j = 0; j < 16; j++) {
            float vv = acc[j][r] * cs4[r] + biasv[j];
            float hv = base[rowb + j * 16] + vv;
            fout[rowb + j * 16] = hv;
            acc[j][r] = hv;
            if (LN) { s1[r] += hv; s2[r] += hv * hv; }
        }
    }
    if (LN) {
#pragma unroll
        for (int r = 0; r < 4; r++) {
#pragma unroll
            for (int mm = 1; mm < 16; mm <<= 1) {
                s1[r] += __shfl_xor(s1[r], mm, 64);
                s2[r] += __shfl_xor(s2[r], mm, 64);
            }
        }
#pragma unroll
        for (int r = 0; r < 4; r++) {
            int m = mb + r;
            if (m >= N_PER) continue;
            float mean = s1[r] * (1.f / 256.f);
            float var = s2[r] * (1.f / 256.f) - mean * mean;
            float rs = rsqrtf(var + 1e-5f);
            float sc = lncs ? lncs[zo * N_PER + m] : 1.f;
            size_t rowb = ((size_t)zo * N_PER + m) * 256 + ml;
#pragma unroll
            for (int j = 0; j < 16; j++) {
                float y = ((acc[j][r] - mean) * rs * gv[j] + bv[j]) * sc;
                hnout[rowb + j * 16] = f2bf(y);
            }
        }
    }
}

// ---------------- m97-style 128x128 dbuf GEMM (qkv / ffn1, bf16 out) ----------------
// MODE 1: q -> bout[0:25.6MB], K/V interleaved -> bout+2*N_PER*256 as [z][m][512]
// MODE 2: ffn1 bf16 gelu, row stride 512
template <int MODE, int KT>
__global__ __launch_bounds__(256, 3)
void k_gemm5(const ushort_t* __restrict__ A, long Az,
             const ushort_t* __restrict__ BT, long Bz,
             const float* __restrict__ bias,
             ushort_t* __restrict__ bout) {
    constexpr int K = KT * 32;
    constexpr int BCOLS = (MODE == 1) ? 768 : 512;
    constexpr int NY = (MODE == 1) ? 6 : 4;
    constexpr int CHUNK = 196 * NY / 8;
    __shared__ __align__(16) ushort_t As[2][128 * 32];
    __shared__ __align__(16) ushort_t Bs[2][128 * 32];
    const int t = threadIdx.x;
    const int lane = t & 63, w = t >> 6;
    const int wm = w & 1, wn = w >> 1;
    const int ml = lane & 15, qo = lane >> 4;
    const int z = blockIdx.z;

    const int lin2 = blockIdx.y * 196 + blockIdx.x;
    const int nid = (lin2 & 7) * CHUNK + (lin2 >> 3);
    const int m0 = (nid / NY) * 128, n0 = (nid % NY) * 128;

    const ushort_t* Ab = A + (long)z * Az;
    const ushort_t* Bb = BT + (long)z * Bz;
    const ushort8v z8 = {0, 0, 0, 0, 0, 0, 0, 0};

    const int srow = t >> 1;
    const int sc0 = (t & 1) * 2;
    const int garow = m0 + srow;
    const long aGb = (long)garow * K + sc0 * 8;
    const long bGb = (long)(n0 + srow) * K + sc0 * 8;
    const int sw0 = srow * 32 + ((sc0 ^ (srow & 3)) << 3);
    const int sw1 = srow * 32 + (((sc0 + 1) ^ (srow & 3)) << 3);
    const bool aok = garow < N_PER;

    int aro[4], bro[4];
#pragma unroll
    for (int i = 0; i < 4; i++) {
        aro[i] = (wm * 64 + i * 16 + ml) * 32 + ((qo ^ (ml & 3)) << 3);
        bro[i] = (wn * 64 + i * 16 + ml) * 32 + ((qo ^ (ml & 3)) << 3);
    }

    floatx4 acc[4][4];
#pragma unroll
    for (int i = 0; i < 4; i++)
#pragma unroll
        for (int j = 0; j < 4; j++) acc[i][j] = (floatx4){0.f, 0.f, 0.f, 0.f};

    {
        ushort8v a0 = aok ? *(const ushort8v*)(Ab + aGb) : z8;
        ushort8v a1 = aok ? *(const ushort8v*)(Ab + aGb + 8) : z8;
        ushort8v b0 = *(const ushort8v*)(Bb + bGb);
        ushort8v b1 = *(const ushort8v*)(Bb + bGb + 8);
        *(ushort8v*)(As[0] + sw0) = a0;
        *(ushort8v*)(As[0] + sw1) = a1;
        *(ushort8v*)(Bs[0] + sw0) = b0;
        *(ushort8v*)(Bs[0] + sw1) = b1;
    }

#pragma unroll
    for (int kt = 0; kt < KT; kt++) {
        __syncthreads();
        const int cur = kt & 1;
        bf16x8 af[4], bf[4];
#pragma unroll
        for (int i = 0; i < 4; i++) {
            af[i] = *(const bf16x8*)(As[cur] + aro[i]);
            bf[i] = *(const bf16x8*)(Bs[cur] + bro[i]);
        }
        if (kt + 1 < KT) {
            const int nk = (kt + 1) * 32;
            ushort8v a0 = aok ? *(const ushort8v*)(Ab + aGb + nk) : z8;
            ushort8v a1 = aok ? *(const ushort8v*)(Ab + aGb + nk + 8) : z8;
            ushort8v b0 = *(const ushort8v*)(Bb + bGb + nk);
            ushort8v b1 = *(const ushort8v*)(Bb + bGb + nk + 8);
            const int nb = cur ^ 1;
            *(ushort8v*)(As[nb] + sw0) = a0;
            *(ushort8v*)(As[nb] + sw1) = a1;
            *(ushort8v*)(Bs[nb] + sw0) = b0;
            *(ushort8v*)(Bs[nb] + sw1) = b1;
        }
#pragma unroll
        for (int i = 0; i < 4; i++)
#pragma unroll
            for (int j = 0; j < 4; j++)
                acc[i][j] = __builtin_amdgcn_mfma_f32_16x16x32_bf16(af[i], bf[j], acc[i][j], 0, 0, 0);
    }

#pragma unroll
    for (int i = 0; i < 4; i++) {
        int mb = m0 + wm * 64 + i * 16 + qo * 4;
#pragma unroll
        for (int j = 0; j < 4; j++) {
            int col = n0 + wn * 64 + j * 16 + ml;
            float bv = bias[z * BCOLS + col];
#pragma unroll
            for (int r = 0; r < 4; r++) {
                int m = mb + r;
                if (m >= N_PER) continue;
                float vv = acc[i][j][r] + bv;
                if (MODE == 2) {
                    vv = fast_gelu(vv);
                    bout[((size_t)z * N_PER + m) * 512 + col] = f2bf(vv);
                } else {
                    int mat = col >> 8, cc = col & 255;
                    if (mat == 0)
                        bout[((size_t)z * N_PER + m) * 256 + cc] = f2bf(vv);
                    else
                        bout[(size_t)2 * N_PER * 256 +
                             ((size_t)z * N_PER + m) * 512 + (size_t)(mat - 1) * 256 + cc] = f2bf(vv);
                }
            }
        }
    }
}

extern "C" void kernel_launch(void* const* d_in, const int* in_sizes, int n_in,
                              void* d_out, int out_size, void* d_ws, size_t ws_size,
                              hipStream_t stream) {
    const float* h_in   = (const float*)d_in[0];
    const int*   e_src  = (const int*)d_in[1];
    const int*   e_dst  = (const int*)d_in[2];
    const float* pre_W  = (const float*)d_in[3];
    const float* pre_b  = (const float*)d_in[4];
    const float* post_W = (const float*)d_in[5];
    const float* post_b = (const float*)d_in[6];
    const float* q_W    = (const float*)d_in[7];
    const float* q_b    = (const float*)d_in[8];
    const float* k_W    = (const float*)d_in[9];
    const float* k_b    = (const float*)d_in[10];
    const float* v_W    = (const float*)d_in[11];
    const float* v_b    = (const float*)d_in[12];
    const float* o_W    = (const float*)d_in[13];
    const float* o_b    = (const float*)d_in[14];
    const float* ffn_W1 = (const float*)d_in[15];
    const float* ffn_b1 = (const float*)d_in[16];
    const float* ffn_W2 = (const float*)d_in[17];
    const float* ffn_b2 = (const float*)d_in[18];
    const float* ln_pre_g  = (const float*)d_in[19];
    const float* ln_pre_b  = (const float*)d_in[20];
    const float* ln_attn_g = (const float*)d_in[21];
    const float* ln_attn_b = (const float*)d_in[22];
    const float* ln_post_g = (const float*)d_in[23];
    const float* ln_post_b = (const float*)d_in[24];
    const float* ln_ffn_g  = (const float*)d_in[25];
    const float* ln_ffn_b  = (const float*)d_in[26];

    float* hout = (float*)d_out;
    char* ws = (char*)d_ws;

    const long AzH = (long)N_PER * HID;

    // workspace layout (bytes)
    ushort_t* hn    = (ushort_t*)(ws + 0);              // 25.6 MB bf16 [2][25000][256]
    ushort_t* qkv   = (ushort_t*)(ws + 25600000);       // q 25.6MB; kv 51.2MB @51.2M
    ushort_t* fb    = (ushort_t*)(ws + 25600000);       // 51.2 MB (aliases q+kv-front; dead by FFN)
    ushort_t* agg   = (ushort_t*)(ws + 102400000);      // 25.6 MB
    ushort_t* wT    = (ushort_t*)(ws + 128000000);      // 2.62 MB
    float* qkvbias  = (float*)(ws + 130621440);
    float* cs       = (float*)(ws + 130627584);
    float* cd       = (float*)(ws + 130827584);
    int* cnt_s      = (int*)(ws + 131027584);
    int* cnt_d      = (int*)(ws + 131227584);
    int* off        = (int*)(ws + 131427584);
    int* cur        = (int*)(ws + 131627592);
    int* csr        = (int*)(ws + 131827592);

    const ushort_t* qkvWT = wT;
    const ushort_t* w1T   = wT + 393216;
    const ushort_t* preP  = wT + 655360;
    const ushort_t* postP = wT + 786432;
    const ushort_t* oP    = wT + 917504;
    const ushort_t* w2P   = wT + 1048576;
    ushort_t* qb  = qkv;                       // [2][25000][256]
    ushort_t* kvb = qkv + 2 * AzH;             // [2][25000][512] K|V interleaved

    hipMemsetAsync(cnt_s, 0, 400000, stream);

    k_convw<<<5120, 256, 0, stream>>>(pre_W, post_W, q_W, k_W, v_W, o_W, ffn_W1, ffn_W2, wT);
    k_packbias<<<6, 256, 0, stream>>>(q_b, k_b, v_b, qkvbias);
    k_count<<<1563, 256, 0, stream>>>(e_src, e_dst, cnt_s, cnt_d);
    k_scale<<<196, 256, 0, stream>>>(cnt_s, cnt_d, cs, cd);
    k_scan<<<2, 1024, 0, stream>>>(cnt_d, off, cur);
    k_fill<<<1563, 256, 0, stream>>>(e_src, e_dst, cur, csr);

    // ---- stage 1: pre hetero-conv (+fused LN_attn) ----
    k_ln<<<12500, 256, 0, stream>>>(h_in, ln_pre_g, ln_pre_b, cs, hn);
    k_gather<<<12500, 256, 0, stream>>>(hn, off, csr, agg);
    k_cgemm<8, true><<<dim3(391, 1, 2), 256, 0, stream>>>(
        agg, AzH, preP, 65536, pre_b, h_in, hout, 1, cd,
        ln_attn_g, ln_attn_b, (const float*)nullptr, hn);

    // ---- stage 2: sparse attention (+fused LN_post w/ cs) ----
    k_gemm5<1, 8><<<dim3(196, 6, 2), 256, 0, stream>>>(hn, AzH, qkvWT, 196608, qkvbias, qkv);
    k_attn<<<12500, 256, 0, stream>>>(qb, kvb, off, csr, agg);
    k_cgemm<8, true><<<dim3(391, 1, 2), 256, 0, stream>>>(
        agg, AzH, oP, 65536, o_b, hout, hout, 0, (const float*)nullptr,
        ln_post_g, ln_post_b, cs, hn);

    // ---- stage 3: post hetero-conv (+fused LN_ffn) ----
    k_gather<<<12500, 256, 0, stream>>>(hn, off, csr, agg);
    k_cgemm<8, true><<<dim3(391, 1, 2), 256, 0, stream>>>(
        agg, AzH, postP, 65536, post_b, hout, hout, 1, cd,
        ln_ffn_g, ln_ffn_b, (const float*)nullptr, hn);

    // ---- stage 4: FFN ----
    k_gemm5<2, 8><<<dim3(196, 4, 2), 256, 0, stream>>>(hn, AzH, w1T, 131072, ffn_b1, fb);
    k_cgemm<16, false><<<dim3(391, 1, 2), 256, 0, stream>>>(
        fb, (long)N_PER * 512, w2P, 131072, ffn_b2, hout, hout, 0, (const float*)nullptr,
        (const float*)nullptr, (const float*)nullptr, (const float*)nullptr, (ushort_t*)nullptr);
}

// Round 14
// 607.737 us; speedup vs baseline: 1.0672x; 1.0201x over previous
//
// build-salt: r14-gemm5-gloadlds
#include <hip/hip_runtime.h>
#include <math.h>

#define N_PER 25000
#define HID 256
#define E_PER 200000

typedef unsigned short ushort_t;
typedef __attribute__((ext_vector_type(8))) unsigned short ushort8v;
typedef __attribute__((ext_vector_type(4))) unsigned short ushort4v;
typedef __attribute__((ext_vector_type(8))) __bf16 bf16x8;
typedef __attribute__((ext_vector_type(4))) float floatx4;

__device__ __forceinline__ float bf2f(unsigned short u) {
    union { unsigned int i; float f; } c; c.i = ((unsigned int)u) << 16; return c.f;
}
__device__ __forceinline__ unsigned short f2bf(float f) {
    union { float f; unsigned int i; } c; c.f = f;
    unsigned int i = c.i;
    return (unsigned short)((i + 0x7FFFu + ((i >> 16) & 1u)) >> 16);
}

// fast GELU: x * sigmoid(1.5957691 * (x + 0.044715 x^3))  (tanh-form approx)
__device__ __forceinline__ float fast_gelu(float x) {
    float u = 1.595769122f * x * (1.f + 0.044715f * x * x);
    float e = __expf(-u);
    return x * __builtin_amdgcn_rcpf(1.f + e);
}

// direct global->LDS 16B copy: per-lane global src, wave-uniform LDS base
// (HW writes base + lane*16). Compiler never auto-emits this (guide CM#1).
__device__ __forceinline__ void g2l16(const ushort_t* g, ushort_t* l) {
    __builtin_amdgcn_global_load_lds((__attribute__((address_space(1))) void*)g,
                                     (__attribute__((address_space(3))) void*)l,
                                     16, 0, 0);
}

// ---------------- degree counting ----------------
__global__ void k_count(const int* __restrict__ es, const int* __restrict__ ed,
                        int* __restrict__ cnt_s, int* __restrict__ cnt_d) {
    int i = blockIdx.x * 256 + threadIdx.x;
    if (i >= 2 * E_PER) return;
    int et = i / E_PER;
    atomicAdd(&cnt_s[et * N_PER + es[i]], 1);
    atomicAdd(&cnt_d[et * N_PER + ed[i]], 1);
}

__global__ void k_scale(const int* __restrict__ cnt_s, const int* __restrict__ cnt_d,
                        float* __restrict__ cs, float* __restrict__ cd) {
    int i = blockIdx.x * 256 + threadIdx.x;
    if (i >= 2 * N_PER) return;
    cs[i] = rsqrtf(fmaxf((float)cnt_s[i], 1.f));
    cd[i] = rsqrtf(fmaxf((float)cnt_d[i], 1.f));
}

// ---------------- CSR build: scan + fill ----------------
__global__ __launch_bounds__(1024) void k_scan(const int* __restrict__ cnt,
                                               int* __restrict__ off, int* __restrict__ cur) {
    int et = blockIdx.x, t = threadIdx.x;
    const int* c = cnt + et * N_PER;
    int loc[25]; int tot = 0;
#pragma unroll
    for (int j = 0; j < 25; j++) {
        int idx = t * 25 + j;
        int v = (idx < N_PER) ? c[idx] : 0;
        loc[j] = tot; tot += v;
    }
    __shared__ int sb[1024];
    sb[t] = tot; __syncthreads();
    for (int d = 1; d < 1024; d <<= 1) {
        int v = (t >= d) ? sb[t - d] : 0;
        __syncthreads();
        sb[t] += v;
        __syncthreads();
    }
    int base = sb[t] - tot;
#pragma unroll
    for (int j = 0; j < 25; j++) {
        int idx = t * 25 + j;
        if (idx <= N_PER) {
            int val = base + loc[j];
            off[et * (N_PER + 1) + idx] = val;
            if (idx < N_PER) cur[et * N_PER + idx] = val;
        }
    }
}

__global__ void k_fill(const int* __restrict__ es, const int* __restrict__ ed,
                       int* __restrict__ cur, int* __restrict__ csr) {
    int i = blockIdx.x * 256 + threadIdx.x;
    if (i >= 2 * E_PER) return;
    int et = i / E_PER;
    int d = ed[i];
    int pos = atomicAdd(&cur[et * N_PER + d], 1);
    csr[et * E_PER + pos] = es[i];
}

// ---------------- weight convert ----------------
__global__ void k_convw(const float* __restrict__ pre, const float* __restrict__ post,
                        const float* __restrict__ qW, const float* __restrict__ kW,
                        const float* __restrict__ vW, const float* __restrict__ oW,
                        const float* __restrict__ w1, const float* __restrict__ w2,
                        ushort_t* __restrict__ out) {
    int i = blockIdx.x * 256 + threadIdx.x;
    if (i >= 1310720) return;
    float v;
    if (i < 393216) {                        // qkv col-major
        int z = (i >= 196608) ? 1 : 0;
        int r = i - z * 196608;
        int row = r >> 8, k = r & 255;
        int mat = row >> 8, c = row & 255;
        const float* src = (mat == 0) ? qW : (mat == 1) ? kW : vW;
        v = src[z * 65536 + k * 256 + c];
    } else if (i < 655360) {                 // w1 col-major
        int j = i - 393216; int z = j >> 17, r = j & 131071;
        int n = r >> 8, k = r & 255;
        v = w1[z * 131072 + k * 512 + n];
    } else if (i < 1048576) {                // pre/post/o packed
        int j = i - 655360; int mat = j >> 17;
        int e = j & 131071; int z = e >> 16; int q2 = e & 65535;
        int kc = q2 >> 13, col = (q2 >> 5) & 255, k32 = q2 & 31;
        const float* src = (mat == 0) ? pre : (mat == 1) ? post : oW;
        v = src[z * 65536 + (kc * 32 + k32) * 256 + col];
    } else {                                 // w2 packed
        int j = i - 1048576; int z = j >> 17; int e = j & 131071;
        int kc = e >> 13, col = (e >> 5) & 255, k32 = e & 31;
        v = w2[z * 131072 + (kc * 32 + k32) * 256 + col];
    }
    out[i] = f2bf(v);
}

// pack q/k/v biases -> [2][768]
__global__ void k_packbias(const float* __restrict__ qb, const float* __restrict__ kb,
                           const float* __restrict__ vb, float* __restrict__ out) {
    int i = blockIdx.x * 256 + threadIdx.x;
    if (i >= 1536) return;
    int z = i / 768, c = i % 768;
    int mat = c >> 8, cc = c & 255;
    const float* src = (mat == 0) ? qb : (mat == 1) ? kb : vb;
    out[i] = src[z * 256 + cc];
}

// ---------------- LayerNorm (+optional cs scale) -> bf16 ----------------
__global__ __launch_bounds__(256) void k_ln(const float* __restrict__ h,
                                            const float* __restrict__ g, const float* __restrict__ b,
                                            const float* __restrict__ cs, ushort_t* __restrict__ out) {
    int lane = threadIdx.x & 63;
    int row = blockIdx.x * 4 + (threadIdx.x >> 6);
    int ty = row >= N_PER;
    float4 x = *(const float4*)(h + (size_t)row * HID + lane * 4);
    float s = x.x + x.y + x.z + x.w;
    float q = x.x * x.x + x.y * x.y + x.z * x.z + x.w * x.w;
    for (int m = 1; m < 64; m <<= 1) {
        s += __shfl_xor(s, m, 64);
        q += __shfl_xor(q, m, 64);
    }
    float mean = s * (1.f / 256.f);
    float var = q * (1.f / 256.f) - mean * mean;
    float rs = rsqrtf(var + 1e-5f);
    float sc = cs ? cs[row] : 1.f;
    int c = lane * 4;
    const float* gp = g + ty * HID + c;
    const float* bp = b + ty * HID + c;
    float xv[4] = {x.x, x.y, x.z, x.w};
    ushort4v o;
#pragma unroll
    for (int i = 0; i < 4; i++) {
        float y = ((xv[i] - mean) * rs * gp[i] + bp[i]) * sc;
        o[i] = f2bf(y);
    }
    *(ushort4v*)(out + (size_t)row * HID + c) = o;
}

// ---------------- conv gather (4-wide unrolled) ----------------
__global__ __launch_bounds__(256) void k_gather(const ushort_t* __restrict__ hn,
                                                const int* __restrict__ off, const int* __restrict__ csr,
                                                ushort_t* __restrict__ agg) {
    int lane = threadIdx.x & 63;
    int row = blockIdx.x * 4 + (threadIdx.x >> 6);
    int dt = row >= N_PER;
    int n = row - dt * N_PER;
    int et = 1 - dt;
    int s0 = off[et * (N_PER + 1) + n], s1 = off[et * (N_PER + 1) + n + 1];
    const ushort_t* hb = hn + (size_t)et * N_PER * HID + lane * 4;
    const int* list = csr + et * E_PER;
    float a0 = 0, a1 = 0, a2 = 0, a3 = 0;
    int e = s0;
    for (; e + 4 <= s1; e += 4) {
        int ia = list[e], ib = list[e + 1], ic = list[e + 2], id = list[e + 3];
        ushort4v ua = *(const ushort4v*)(hb + (size_t)ia * HID);
        ushort4v ub = *(const ushort4v*)(hb + (size_t)ib * HID);
        ushort4v uc = *(const ushort4v*)(hb + (size_t)ic * HID);
        ushort4v ud = *(const ushort4v*)(hb + (size_t)id * HID);
        a0 += bf2f(ua[0]) + bf2f(ub[0]) + bf2f(uc[0]) + bf2f(ud[0]);
        a1 += bf2f(ua[1]) + bf2f(ub[1]) + bf2f(uc[1]) + bf2f(ud[1]);
        a2 += bf2f(ua[2]) + bf2f(ub[2]) + bf2f(uc[2]) + bf2f(ud[2]);
        a3 += bf2f(ua[3]) + bf2f(ub[3]) + bf2f(uc[3]) + bf2f(ud[3]);
    }
    for (; e < s1; ++e) {
        int src = list[e];
        ushort4v u = *(const ushort4v*)(hb + (size_t)src * HID);
        a0 += bf2f(u[0]); a1 += bf2f(u[1]); a2 += bf2f(u[2]); a3 += bf2f(u[3]);
    }
    ushort4v o; o[0] = f2bf(a0); o[1] = f2bf(a1); o[2] = f2bf(a2); o[3] = f2bf(a3);
    *(ushort4v*)(agg + ((size_t)et * N_PER + n) * HID + lane * 4) = o;
}

// ---------------- fused edge softmax attention (4-wide, interleaved KV) ----------------
__global__ __launch_bounds__(256) void k_attn(const ushort_t* __restrict__ q,
                                              const ushort_t* __restrict__ kv,
                                              const int* __restrict__ off, const int* __restrict__ csr,
                                              ushort_t* __restrict__ outb) {
    int lane = threadIdx.x & 63;
    int row = blockIdx.x * 4 + (threadIdx.x >> 6);
    int dt = row >= N_PER;
    int n = row - dt * N_PER;
    int et = 1 - dt;
    int s0 = off[et * (N_PER + 1) + n], s1 = off[et * (N_PER + 1) + n + 1];
    ushort4v qu = *(const ushort4v*)(q + (size_t)row * HID + lane * 4);
    float q0 = bf2f(qu[0]), q1 = bf2f(qu[1]), q2 = bf2f(qu[2]), q3 = bf2f(qu[3]);
    const ushort_t* kvb = kv + (size_t)et * N_PER * 512 + lane * 4;
    const int* list = csr + et * E_PER;
    float l = 0.f;
    float O0 = 0, O1 = 0, O2 = 0, O3 = 0;
    int e = s0;
    for (; e + 4 <= s1; e += 4) {
        const ushort_t* p0 = kvb + (size_t)list[e] * 512;
        const ushort_t* p1 = kvb + (size_t)list[e + 1] * 512;
        const ushort_t* p2 = kvb + (size_t)list[e + 2] * 512;
        const ushort_t* p3 = kvb + (size_t)list[e + 3] * 512;
        ushort4v k0 = *(const ushort4v*)p0, v0 = *(const ushort4v*)(p0 + 256);
        ushort4v k1 = *(const ushort4v*)p1, v1 = *(const ushort4v*)(p1 + 256);
        ushort4v k2 = *(const ushort4v*)p2, v2 = *(const ushort4v*)(p2 + 256);
        ushort4v k3 = *(const ushort4v*)p3, v3 = *(const ushort4v*)(p3 + 256);
        float d0 = q0 * bf2f(k0[0]) + q1 * bf2f(k0[1]) + q2 * bf2f(k0[2]) + q3 * bf2f(k0[3]);
        float d1 = q0 * bf2f(k1[0]) + q1 * bf2f(k1[1]) + q2 * bf2f(k1[2]) + q3 * bf2f(k1[3]);
        float d2 = q0 * bf2f(k2[0]) + q1 * bf2f(k2[1]) + q2 * bf2f(k2[2]) + q3 * bf2f(k2[3]);
        float d3 = q0 * bf2f(k3[0]) + q1 * bf2f(k3[1]) + q2 * bf2f(k3[2]) + q3 * bf2f(k3[3]);
        d0 += __shfl_xor(d0, 1, 64); d1 += __shfl_xor(d1, 1, 64);
        d2 += __shfl_xor(d2, 1, 64); d3 += __shfl_xor(d3, 1, 64);
        d0 += __shfl_xor(d0, 2, 64); d1 += __shfl_xor(d1, 2, 64);
        d2 += __shfl_xor(d2, 2, 64); d3 += __shfl_xor(d3, 2, 64);
        d0 += __shfl_xor(d0, 4, 64); d1 += __shfl_xor(d1, 4, 64);
        d2 += __shfl_xor(d2, 4, 64); d3 += __shfl_xor(d3, 4, 64);
        float s0f = fminf(5.f, fmaxf(-5.f, d0 * 0.17677669529663687f));
        float s1f = fminf(5.f, fmaxf(-5.f, d1 * 0.17677669529663687f));
        float s2f = fminf(5.f, fmaxf(-5.f, d2 * 0.17677669529663687f));
        float s3f = fminf(5.f, fmaxf(-5.f, d3 * 0.17677669529663687f));
        float e0 = __expf(s0f), e1 = __expf(s1f), e2 = __expf(s2f), e3 = __expf(s3f);
        l += (e0 + e1) + (e2 + e3);
        O0 += e0 * bf2f(v0[0]) + e1 * bf2f(v1[0]) + e2 * bf2f(v2[0]) + e3 * bf2f(v3[0]);
        O1 += e0 * bf2f(v0[1]) + e1 * bf2f(v1[1]) + e2 * bf2f(v2[1]) + e3 * bf2f(v3[1]);
        O2 += e0 * bf2f(v0[2]) + e1 * bf2f(v1[2]) + e2 * bf2f(v2[2]) + e3 * bf2f(v3[2]);
        O3 += e0 * bf2f(v0[3]) + e1 * bf2f(v1[3]) + e2 * bf2f(v2[3]) + e3 * bf2f(v3[3]);
    }
    for (; e < s1; ++e) {
        const ushort_t* p = kvb + (size_t)list[e] * 512;
        ushort4v ku = *(const ushort4v*)p;
        ushort4v vu = *(const ushort4v*)(p + 256);
        float d = q0 * bf2f(ku[0]) + q1 * bf2f(ku[1]) + q2 * bf2f(ku[2]) + q3 * bf2f(ku[3]);
        d += __shfl_xor(d, 1, 64);
        d += __shfl_xor(d, 2, 64);
        d += __shfl_xor(d, 4, 64);
        float s = fminf(5.f, fmaxf(-5.f, d * 0.17677669529663687f));
        float p2 = __expf(s);
        l += p2;
        O0 += p2 * bf2f(vu[0]); O1 += p2 * bf2f(vu[1]);
        O2 += p2 * bf2f(vu[2]); O3 += p2 * bf2f(vu[3]);
    }
    float inv = (l > 0.f) ? 1.f / l : 0.f;
    ushort4v o;
    o[0] = f2bf(O0 * inv); o[1] = f2bf(O1 * inv); o[2] = f2bf(O2 * inv); o[3] = f2bf(O3 * inv);
    *(ushort4v*)(outb + (size_t)row * HID + lane * 4) = o;
}

// ---------------- full-row conv GEMM + residual + fused LayerNorm (v2) ----------------
// 64 rows x 256 cols per block, 256 threads = 4 waves; grid 391x2 -> ~3 blocks/CU.
// Bs double-buffered, one barrier per kt; A 1-deep prefetch; Bs XOR swizzle
// ((col>>1)&3)<<4 on both sides kills the 8-way ds_read bank conflict.
template <int KT, bool LN>
__global__ __launch_bounds__(256, 3)
void k_cgemm(const ushort_t* __restrict__ A, long Az,
             const ushort_t* __restrict__ Bpk, long Bz,
             const float* __restrict__ bias,
             const float* __restrict__ base, float* __restrict__ fout, int swapz,
             const float* __restrict__ convscale,
             const float* __restrict__ g, const float* __restrict__ b,
             const float* __restrict__ lncs, ushort_t* __restrict__ hnout) {
    constexpr int K = KT * 32;
    __shared__ __align__(16) ushort_t Bs[2][256 * 32];   // 2 x 16KB
    const int t = threadIdx.x;
    const int lane = t & 63, w = t >> 6;                 // 4 waves
    const int ml = lane & 15, qo = lane >> 4;
    const int z = blockIdx.z;
    const int m0 = blockIdx.x * 64;
    const ushort_t* Ab = A + (long)z * Az;
    const ushort_t* Bp = Bpk + (long)z * Bz;
    const ushort8v z8 = {0, 0, 0, 0, 0, 0, 0, 0};

    const int arow = m0 + w * 16 + ml;
    const bool aok = arow < N_PER;
    const long abase = (long)arow * K + qo * 8;

    int woff[4];
#pragma unroll
    for (int c = 0; c < 4; c++) {
        int u = t * 8 + c * 2048;
        int col = u >> 5;
        woff[c] = u * 2 ^ (((col >> 1) & 3) << 4);
    }
    const int rbase = ml * 64 + ((qo << 4) ^ (((ml >> 1) & 3) << 4));

    floatx4 acc[16];
#pragma unroll
    for (int j = 0; j < 16; j++) acc[j] = (floatx4){0.f, 0.f, 0.f, 0.f};

    ushort8v bst[4];
#pragma unroll
    for (int c = 0; c < 4; c++) bst[c] = *(const ushort8v*)(Bp + t * 8 + c * 2048);
    ushort8v aNext = aok ? *(const ushort8v*)(Ab + abase) : z8;
#pragma unroll
    for (int c = 0; c < 4; c++) *(ushort8v*)((char*)Bs[0] + woff[c]) = bst[c];
    __syncthreads();

    for (int kt = 0; kt < KT; kt++) {
        const int cur = kt & 1;
        ushort8v aCur = aNext;
        if (kt + 1 < KT) {
            const ushort_t* gs = Bp + (long)(kt + 1) * 8192;
#pragma unroll
            for (int c = 0; c < 4; c++) bst[c] = *(const ushort8v*)(gs + t * 8 + c * 2048);
            aNext = aok ? *(const ushort8v*)(Ab + abase + (kt + 1) * 32) : z8;
        }
#pragma unroll
        for (int j = 0; j < 16; j++) {
            bf16x8 bfr = *(const bf16x8*)((const char*)Bs[cur] + j * 1024 + rbase);
            acc[j] = __builtin_amdgcn_mfma_f32_16x16x32_bf16(*(bf16x8*)&aCur, bfr, acc[j], 0, 0, 0);
        }
        if (kt + 1 < KT) {
#pragma unroll
            for (int c = 0; c < 4; c++) *(ushort8v*)((char*)Bs[cur ^ 1] + woff[c]) = bst[c];
        }
        __syncthreads();
    }

    const int zo = swapz ? 1 - z : z;
    const int mb = m0 + w * 16 + qo * 4;
    float cs4[4];
#pragma unroll
    for (int r = 0; r < 4; r++)
        cs4[r] = (convscale && mb + r < N_PER) ? convscale[z * N_PER + mb + r] : 1.f;
    float biasv[16], gv[16], bv[16];
#pragma unroll
    for (int j = 0; j < 16; j++) {
        int col = j * 16 + ml;
        biasv[j] = bias[z * 256 + col];
        if (LN) { gv[j] = g[zo * 256 + col]; bv[j] = b[zo * 256 + col]; }
    }

    float s1[4] = {0, 0, 0, 0}, s2[4] = {0, 0, 0, 0};
#pragma unroll
    for (int r = 0; r < 4; r++) {
        int m = mb + r;
        if (m >= N_PER) continue;
        size_t rowb = ((size_t)zo * N_PER + m) * 256 + ml;
#pragma unroll
        for (int j = 0; j < 16; j++) {
            float vv = acc[j][r] * cs4[r] + biasv[j];
            float hv = base[rowb + j * 16] + vv;
            fout[rowb + j * 16] = hv;
            acc[j][r] = hv;
            if (LN) { s1[r] += hv; s2[r] += hv * hv; }
        }
    }
    if (LN) {
#pragma unroll
        for (int r = 0; r < 4; r++) {
#pragma unroll
            for (int mm = 1; mm < 16; mm <<= 1) {
                s1[r] += __shfl_xor(s1[r], mm, 64);
                s2[r] += __shfl_xor(s2[r], mm, 64);
            }
        }
#pragma unroll
        for (int r = 0; r < 4; r++) {
            int m = mb + r;
            if (m >= N_PER) continue;
            float mean = s1[r] * (1.f / 256.f);
            float var = s2[r] * (1.f / 256.f) - mean * mean;
            float rs = rsqrtf(var + 1e-5f);
            float sc = lncs ? lncs[zo * N_PER + m] : 1.f;
            size_t rowb = ((size_t)zo * N_PER + m) * 256 + ml;
#pragma unroll
            for (int j = 0; j < 16; j++) {
                float y = ((acc[j][r] - mean) * rs * gv[j] + bv[j]) * sc;
                hnout[rowb + j * 16] = f2bf(y);
            }
        }
    }
}

// ---------------- 128x128 dbuf GEMM via global_load_lds (qkv / ffn1) ----------------
// Staging rewritten from reg-staging (global->VGPR->ds_write) to DIRECT
// global_load_lds dwordx4 (m151: 874 vs 646 TF at this very tile structure).
// LDS dest is linear (wave-uniform base + lane*16); the XOR swizzle moves to
// the SOURCE address (involution; rule 21 both-sides): LDS chunk d (16B)
// holds global (row=d>>2, col8=(d&3)^(row&3)). Read offsets unchanged.
// OOB A-rows (>=N_PER) read adjacent workspace -> garbage rows discarded by
// the epilogue guard (MFMA rows independent).
template <int MODE, int KT>
__global__ __launch_bounds__(256, 3)
void k_gemm5(const ushort_t* __restrict__ A, long Az,
             const ushort_t* __restrict__ BT, long Bz,
             const float* __restrict__ bias,
             ushort_t* __restrict__ bout) {
    constexpr int K = KT * 32;
    constexpr int BCOLS = (MODE == 1) ? 768 : 512;
    constexpr int NY = (MODE == 1) ? 6 : 4;
    constexpr int CHUNK = 196 * NY / 8;
    __shared__ __align__(16) ushort_t As[2][128 * 32];
    __shared__ __align__(16) ushort_t Bs[2][128 * 32];
    const int t = threadIdx.x;
    const int lane = t & 63, w = t >> 6;
    const int wm = w & 1, wn = w >> 1;
    const int ml = lane & 15, qo = lane >> 4;
    const int z = blockIdx.z;

    const int lin2 = blockIdx.y * 196 + blockIdx.x;
    const int nid = (lin2 & 7) * CHUNK + (lin2 >> 3);
    const int m0 = (nid / NY) * 128, n0 = (nid % NY) * 128;

    const ushort_t* Ab = A + (long)z * Az;
    const ushort_t* Bb = BT + (long)z * Bz;

    // staging: thread t owns 16B chunks d0=t (rows 0..63) and d1=t+256 (rows 64..127)
    const int d0r = t >> 2, d0c = t & 3;
    const int d1r = 64 + d0r;
    const long aS0 = (long)(m0 + d0r) * K + ((d0c ^ (d0r & 3)) * 8);
    const long aS1 = (long)(m0 + d1r) * K + ((d0c ^ (d1r & 3)) * 8);
    const long bS0 = (long)(n0 + d0r) * K + ((d0c ^ (d0r & 3)) * 8);
    const long bS1 = (long)(n0 + d1r) * K + ((d0c ^ (d1r & 3)) * 8);
    const int lw = w * 512;                  // wave's linear LDS ushort offset

    int aro[4], bro[4];
#pragma unroll
    for (int i = 0; i < 4; i++) {
        aro[i] = (wm * 64 + i * 16 + ml) * 32 + ((qo ^ (ml & 3)) << 3);
        bro[i] = (wn * 64 + i * 16 + ml) * 32 + ((qo ^ (ml & 3)) << 3);
    }

    floatx4 acc[4][4];
#pragma unroll
    for (int i = 0; i < 4; i++)
#pragma unroll
        for (int j = 0; j < 4; j++) acc[i][j] = (floatx4){0.f, 0.f, 0.f, 0.f};

    // prologue: stage kt=0 directly to LDS
    g2l16(Ab + aS0, &As[0][lw]);
    g2l16(Ab + aS1, &As[0][2048 + lw]);
    g2l16(Bb + bS0, &Bs[0][lw]);
    g2l16(Bb + bS1, &Bs[0][2048 + lw]);
    __syncthreads();

#pragma unroll
    for (int kt = 0; kt < KT; kt++) {
        const int cur = kt & 1;
        if (kt + 1 < KT) {                   // prefetch next tile while computing
            const long ko = (long)(kt + 1) * 32;
            const int nb = cur ^ 1;
            g2l16(Ab + aS0 + ko, &As[nb][lw]);
            g2l16(Ab + aS1 + ko, &As[nb][2048 + lw]);
            g2l16(Bb + bS0 + ko, &Bs[nb][lw]);
            g2l16(Bb + bS1 + ko, &Bs[nb][2048 + lw]);
        }
        bf16x8 af[4], bf[4];
#pragma unroll
        for (int i = 0; i < 4; i++) {
            af[i] = *(const bf16x8*)(As[cur] + aro[i]);
            bf[i] = *(const bf16x8*)(Bs[cur] + bro[i]);
        }
#pragma unroll
        for (int i = 0; i < 4; i++)
#pragma unroll
            for (int j = 0; j < 4; j++)
                acc[i][j] = __builtin_amdgcn_mfma_f32_16x16x32_bf16(af[i], bf[j], acc[i][j], 0, 0, 0);
        __syncthreads();                     // drains prefetch + lds reads
    }

#pragma unroll
    for (int i = 0; i < 4; i++) {
        int mb = m0 + wm * 64 + i * 16 + qo * 4;
#pragma unroll
        for (int j = 0; j < 4; j++) {
            int col = n0 + wn * 64 + j * 16 + ml;
            float bv = bias[z * BCOLS + col];
#pragma unroll
            for (int r = 0; r < 4; r++) {
                int m = mb + r;
                if (m >= N_PER) continue;
                float vv = acc[i][j][r] + bv;
                if (MODE == 2) {
                    vv = fast_gelu(vv);
                    bout[((size_t)z * N_PER + m) * 512 + col] = f2bf(vv);
                } else {
                    int mat = col >> 8, cc = col & 255;
                    if (mat == 0)
                        bout[((size_t)z * N_PER + m) * 256 + cc] = f2bf(vv);
                    else
                        bout[(size_t)2 * N_PER * 256 +
                             ((size_t)z * N_PER + m) * 512 + (size_t)(mat - 1) * 256 + cc] = f2bf(vv);
                }
            }
        }
    }
}

extern "C" void kernel_launch(void* const* d_in, const int* in_sizes, int n_in,
                              void* d_out, int out_size, void* d_ws, size_t ws_size,
                              hipStream_t stream) {
    const float* h_in   = (const float*)d_in[0];
    const int*   e_src  = (const int*)d_in[1];
    const int*   e_dst  = (const int*)d_in[2];
    const float* pre_W  = (const float*)d_in[3];
    const float* pre_b  = (const float*)d_in[4];
    const float* post_W = (const float*)d_in[5];
    const float* post_b = (const float*)d_in[6];
    const float* q_W    = (const float*)d_in[7];
    const float* q_b    = (const float*)d_in[8];
    const float* k_W    = (const float*)d_in[9];
    const float* k_b    = (const float*)d_in[10];
    const float* v_W    = (const float*)d_in[11];
    const float* v_b    = (const float*)d_in[12];
    const float* o_W    = (const float*)d_in[13];
    const float* o_b    = (const float*)d_in[14];
    const float* ffn_W1 = (const float*)d_in[15];
    const float* ffn_b1 = (const float*)d_in[16];
    const float* ffn_W2 = (const float*)d_in[17];
    const float* ffn_b2 = (const float*)d_in[18];
    const float* ln_pre_g  = (const float*)d_in[19];
    const float* ln_pre_b  = (const float*)d_in[20];
    const float* ln_attn_g = (const float*)d_in[21];
    const float* ln_attn_b = (const float*)d_in[22];
    const float* ln_post_g = (const float*)d_in[23];
    const float* ln_post_b = (const float*)d_in[24];
    const float* ln_ffn_g  = (const float*)d_in[25];
    const float* ln_ffn_b  = (const float*)d_in[26];

    float* hout = (float*)d_out;
    char* ws = (char*)d_ws;

    const long AzH = (long)N_PER * HID;

    // workspace layout (bytes)
    ushort_t* hn    = (ushort_t*)(ws + 0);              // 25.6 MB bf16 [2][25000][256]
    ushort_t* qkv   = (ushort_t*)(ws + 25600000);       // q 25.6MB; kv 51.2MB @51.2M
    ushort_t* fb    = (ushort_t*)(ws + 25600000);       // 51.2 MB (aliases q+kv-front; dead by FFN)
    ushort_t* agg   = (ushort_t*)(ws + 102400000);      // 25.6 MB
    ushort_t* wT    = (ushort_t*)(ws + 128000000);      // 2.62 MB
    float* qkvbias  = (float*)(ws + 130621440);
    float* cs       = (float*)(ws + 130627584);
    float* cd       = (float*)(ws + 130827584);
    int* cnt_s      = (int*)(ws + 131027584);
    int* cnt_d      = (int*)(ws + 131227584);
    int* off        = (int*)(ws + 131427584);
    int* cur        = (int*)(ws + 131627592);
    int* csr        = (int*)(ws + 131827592);

    const ushort_t* qkvWT = wT;
    const ushort_t* w1T   = wT + 393216;
    const ushort_t* preP  = wT + 655360;
    const ushort_t* postP = wT + 786432;
    const ushort_t* oP    = wT + 917504;
    const ushort_t* w2P   = wT + 1048576;
    ushort_t* qb  = qkv;                       // [2][25000][256]
    ushort_t* kvb = qkv + 2 * AzH;             // [2][25000][512] K|V interleaved

    hipMemsetAsync(cnt_s, 0, 400000, stream);

    k_convw<<<5120, 256, 0, stream>>>(pre_W, post_W, q_W, k_W, v_W, o_W, ffn_W1, ffn_W2, wT);
    k_packbias<<<6, 256, 0, stream>>>(q_b, k_b, v_b, qkvbias);
    k_count<<<1563, 256, 0, stream>>>(e_src, e_dst, cnt_s, cnt_d);
    k_scale<<<196, 256, 0, stream>>>(cnt_s, cnt_d, cs, cd);
    k_scan<<<2, 1024, 0, stream>>>(cnt_d, off, cur);
    k_fill<<<1563, 256, 0, stream>>>(e_src, e_dst, cur, csr);

    // ---- stage 1: pre hetero-conv (+fused LN_attn) ----
    k_ln<<<12500, 256, 0, stream>>>(h_in, ln_pre_g, ln_pre_b, cs, hn);
    k_gather<<<12500, 256, 0, stream>>>(hn, off, csr, agg);
    k_cgemm<8, true><<<dim3(391, 1, 2), 256, 0, stream>>>(
        agg, AzH, preP, 65536, pre_b, h_in, hout, 1, cd,
        ln_attn_g, ln_attn_b, (const float*)nullptr, hn);

    // ---- stage 2: sparse attention (+fused LN_post w/ cs) ----
    k_gemm5<1, 8><<<dim3(196, 6, 2), 256, 0, stream>>>(hn, AzH, qkvWT, 196608, qkvbias, qkv);
    k_attn<<<12500, 256, 0, stream>>>(qb, kvb, off, csr, agg);
    k_cgemm<8, true><<<dim3(391, 1, 2), 256, 0, stream>>>(
        agg, AzH, oP, 65536, o_b, hout, hout, 0, (const float*)nullptr,
        ln_post_g, ln_post_b, cs, hn);

    // ---- stage 3: post hetero-conv (+fused LN_ffn) ----
    k_gather<<<12500, 256, 0, stream>>>(hn, off, csr, agg);
    k_cgemm<8, true><<<dim3(391, 1, 2), 256, 0, stream>>>(
        agg, AzH, postP, 65536, post_b, hout, hout, 1, cd,
        ln_ffn_g, ln_ffn_b, (const float*)nullptr, hn);

    // ---- stage 4: FFN ----
    k_gemm5<2, 8><<<dim3(196, 4, 2), 256, 0, stream>>>(hn, AzH, w1T, 131072, ffn_b1, fb);
    k_cgemm<16, false><<<dim3(391, 1, 2), 256, 0, stream>>>(
        fb, (long)N_PER * 512, w2P, 131072, ffn_b2, hout, hout, 0, (const float*)nullptr,
        (const float*)nullptr, (const float*)nullptr, (const float*)nullptr, (ushort_t*)nullptr);
}